// Round 8
// baseline (407.772 us; speedup 1.0000x reference)
//
#include <hip/hip_runtime.h>
#include <hip/hip_bf16.h>

using bf16 = __hip_bfloat16;
typedef unsigned int uint;
typedef unsigned short ushort;
typedef __attribute__((ext_vector_type(8))) short bf16x8;
typedef __attribute__((ext_vector_type(4))) float f32x4;

// Shapes: B=2, S=512, SD=512, P=256, PD=128, AD=64, H=256
// All global tensors are f32.

__device__ __forceinline__ float bfraw(uint u) { return __uint_as_float(u << 16); }
__device__ __forceinline__ ushort f2bf(float f) {
    bf16 h = __float2bfloat16(f);
    return *reinterpret_cast<ushort*>(&h);
}
__device__ __forceinline__ float lbf(ushort u) { return __uint_as_float(((uint)u) << 16); }

#define MFMA_B16(a, b, c) __builtin_amdgcn_mfma_f32_16x16x32_bf16((a), (b), (c), 0, 0, 0)

// ---------------------------------------------------------------------------
// A: LayerNorm(seq) over SD=512 + avg-pool row pairs -> x2 f32. 512 blocks.
// ---------------------------------------------------------------------------
__global__ __launch_bounds__(256) void k_ln_pool(
    const float* __restrict__ seq, const float* __restrict__ g,
    const float* __restrict__ be, float* __restrict__ x2)
{
    __shared__ float red[4][4];
    int bp = blockIdx.x;
    int t  = threadIdx.x;
    const float* r0 = seq + (size_t)(bp * 2) * 512;
    const float* r1 = r0 + 512;

    float a0 = r0[t], a1 = r0[t + 256];
    float c0 = r1[t], c1 = r1[t + 256];

    float s0 = a0 + a1, q0 = a0 * a0 + a1 * a1;
    float s1 = c0 + c1, q1 = c0 * c0 + c1 * c1;
#pragma unroll
    for (int off = 32; off; off >>= 1) {
        s0 += __shfl_xor(s0, off); q0 += __shfl_xor(q0, off);
        s1 += __shfl_xor(s1, off); q1 += __shfl_xor(q1, off);
    }
    int w = t >> 6, l = t & 63;
    if (l == 0) { red[0][w] = s0; red[1][w] = q0; red[2][w] = s1; red[3][w] = q1; }
    __syncthreads();
    s0 = red[0][0] + red[0][1] + red[0][2] + red[0][3];
    q0 = red[1][0] + red[1][1] + red[1][2] + red[1][3];
    s1 = red[2][0] + red[2][1] + red[2][2] + red[2][3];
    q1 = red[3][0] + red[3][1] + red[3][2] + red[3][3];

    const float inv = 1.0f / 512.0f;
    float mu0 = s0 * inv, var0 = q0 * inv - mu0 * mu0, rs0 = rsqrtf(var0 + 1e-5f);
    float mu1 = s1 * inv, var1 = q1 * inv - mu1 * mu1, rs1 = rsqrtf(var1 + 1e-5f);

    float g0 = g[t], g1 = g[t + 256];
    float e0 = be[t], e1 = be[t + 256];

    float o0 = 0.5f * ((a0 - mu0) * rs0 * g0 + e0 + (c0 - mu1) * rs1 * g0 + e0);
    float o1 = 0.5f * ((a1 - mu0) * rs0 * g1 + e1 + (c1 - mu1) * rs1 * g1 + e1);

    float* xo = x2 + (size_t)bp * 512;
    xo[t] = o0; xo[t + 256] = o1;
}

// ---------------------------------------------------------------------------
// B: A2 = (x@Wq + gelu(x)@Wyq)@Wout + bout ; C2 = (x@Wk + gelu(x)@Wyk)@Wout
// ---------------------------------------------------------------------------
__global__ __launch_bounds__(128) void k_proj(
    const float* __restrict__ x2,
    const float* __restrict__ Wq, const float* __restrict__ Wk,
    const float* __restrict__ Wyq, const float* __restrict__ Wyk,
    const float* __restrict__ Wout, const float* __restrict__ bout,
    float* __restrict__ a2, float* __restrict__ c2)
{
    __shared__ float xr[512], gxr[512], ar[128], cr[128];
    int row = blockIdx.x;
    int t   = threadIdx.x;

    for (int u = t; u < 512; u += 128) {
        float v = x2[(size_t)row * 512 + u];
        xr[u]  = v;
        gxr[u] = 0.5f * v * (1.0f + erff(v * 0.70710678118654752f));
    }
    __syncthreads();

    float a = 0.f, c = 0.f;
    for (int s = 0; s < 512; s++) {
        float xs = xr[s], gs = gxr[s];
        a += xs * Wq[s * 128 + t] + gs * Wyq[s * 128 + t];
        c += xs * Wk[s * 128 + t] + gs * Wyk[s * 128 + t];
    }
    ar[t] = a; cr[t] = c;
    __syncthreads();

    float A = bout[t], C = 0.f;
    for (int u = 0; u < 128; u++) {
        float wv = Wout[u * 128 + t];
        A += ar[u] * wv;
        C += cr[u] * wv;
    }
    a2[(size_t)row * 128 + t] = A;
    c2[(size_t)row * 128 + t] = C;
}

// ---------------------------------------------------------------------------
// W: Wd2 = Wdist(3x128) @ Wout(128x128)
// ---------------------------------------------------------------------------
__global__ __launch_bounds__(128) void k_wd2(
    const float* __restrict__ Wdist, const float* __restrict__ Wout,
    float* __restrict__ wd2)
{
    int t = threadIdx.x;
#pragma unroll
    for (int f = 0; f < 3; f++) {
        float acc = 0.f;
        for (int u = 0; u < 128; u++)
            acc += Wdist[f * 128 + u] * Wout[u * 128 + t];
        wd2[f * 128 + t] = acc;
    }
}

// ---------------------------------------------------------------------------
// WT prep: wT[c][k] (bf16, [64][128]) = W[k][c] (f32, [128][64]) for Wrq/Wrk/Wrv
// ---------------------------------------------------------------------------
__global__ __launch_bounds__(512) void k_wt(
    const float* __restrict__ Wrq, const float* __restrict__ Wrk,
    const float* __restrict__ Wrv, ushort* __restrict__ wqT,
    ushort* __restrict__ wkT, ushort* __restrict__ wvT)
{
    int idx = blockIdx.x * 512 + threadIdx.x;       // 0 .. 3*8192
    int m = idx >> 13;
    int e = idx & 8191;
    int c = e >> 7, k = e & 127;
    const float* W = (m == 0) ? Wrq : (m == 1) ? Wrk : Wrv;
    ushort* T = (m == 0) ? wqT : (m == 1) ? wkT : wvT;
    T[e] = f2bf(W[k * 64 + c]);
}

// ---------------------------------------------------------------------------
// WT prep 2 (MLP): w1T[c][k] = W1[k][c] (c<256,k<128); w2T[c][k] = W2[k][c]
// ---------------------------------------------------------------------------
__global__ __launch_bounds__(512) void k_wt12(
    const float* __restrict__ W1, const float* __restrict__ W2,
    ushort* __restrict__ w1T, ushort* __restrict__ w2T)
{
    int idx = blockIdx.x * 512 + threadIdx.x;   // 0 .. 65536
    if (idx < 32768) {
        int c = idx >> 7, k = idx & 127;        // W1 [128][256] -> w1T [256][128]
        w1T[idx] = f2bf(W1[k * 256 + c]);
    } else {
        int e = idx - 32768;
        int c = e >> 8, k = e & 255;            // W2 [256][128] -> w2T [128][256]
        w2T[e] = f2bf(W2[k * 128 + c]);
    }
}

// ---------------------------------------------------------------------------
// C: x[b,i,j,d] = pair + A2[b,i,d] + C2[b,j,d] + feats(i,j)·Wd2[:,d] -> d_out
// ---------------------------------------------------------------------------
__global__ __launch_bounds__(256) void k_assemble(
    const float* __restrict__ pair, const float* __restrict__ a2,
    const float* __restrict__ c2, const float* __restrict__ wd2,
    float* __restrict__ xout)
{
    size_t idx = (size_t)blockIdx.x * 256 + threadIdx.x;
    int d = (int)(idx & 127);
    size_t r = idx >> 7;
    int j = (int)(r & 255); r >>= 8;
    int i = (int)(r & 255);
    int b = (int)(r >> 8);

    float ds = fabsf((float)(i - j)) * (1.0f / 255.0f);
    float sg = (float)((i > j) - (i < j));
    float ex = __expf(-ds);

    float v = pair[idx]
            + a2[(size_t)(b * 256 + i) * 128 + d]
            + c2[(size_t)(b * 256 + j) * 128 + d]
            + ds * wd2[d] + sg * wd2[128 + d] + ex * wd2[256 + d];
    xout[idx] = v;
}

// ---------------------------------------------------------------------------
// E (MFMA attention): per (b,i) slice [256 rows x 128].  (unchanged, proven)
// ---------------------------------------------------------------------------
__global__ __launch_bounds__(512, 2) void k_attn_mfma(
    float* __restrict__ x,
    const float* __restrict__ rn_g, const float* __restrict__ rn_b,
    const ushort* __restrict__ wqT, const ushort* __restrict__ wkT,
    const ushort* __restrict__ wvT, const float* __restrict__ brv,
    const float* __restrict__ Wro, const float* __restrict__ bro)
{
    __shared__ __align__(16) unsigned char smem[131072];

    int tid = threadIdx.x;
    int w  = tid >> 6;
    int l  = tid & 63;
    int g  = l >> 4;      // 0..3  (k-group)
    int lr = l & 15;      // 0..15 (row/col within tile)
    size_t base = (size_t)blockIdx.x * 32768;

    float gl0 = rn_g[l], gl1 = rn_g[l + 64];
    float el0 = rn_b[l], el1 = rn_b[l + 64];

    // ================= QKV (two halves of 128 rows) =================
    for (int h = 0; h < 2; h++) {
        for (int rr = 0; rr < 16; rr++) {
            int rloc = 16 * w + rr;
            size_t ro = base + (size_t)(128 * h + rloc) * 128;
            float x0 = x[ro + l], x1 = x[ro + l + 64];
            float s = x0 + x1, q = x0 * x0 + x1 * x1;
#pragma unroll
            for (int off = 32; off; off >>= 1) { s += __shfl_xor(s, off); q += __shfl_xor(q, off); }
            float mu = s * (1.0f / 128.0f);
            float var = q * (1.0f / 128.0f) - mu * mu;
            float rs = rsqrtf(var + 1e-5f);
            int sw = (rloc & 7) << 4;
            *(ushort*)(smem + 65536 + rloc * 256 + ((2 * l) ^ sw))        = f2bf((x0 - mu) * rs * gl0 + el0);
            *(ushort*)(smem + 65536 + rloc * 256 + ((2 * (l + 64)) ^ sw)) = f2bf((x1 - mu) * rs * gl1 + el1);
        }
        asm volatile("s_waitcnt lgkmcnt(0)" ::: "memory");

        bf16x8 afr[4];
        int arow = 16 * w + lr;
#pragma unroll
        for (int kf = 0; kf < 4; kf++) {
            int ab = 65536 + arow * 256 + ((16 * g + 64 * kf) ^ ((arow & 7) << 4));
            afr[kf] = *(const bf16x8*)(smem + ab);
        }
#pragma unroll
        for (int m = 0; m < 3; m++) {
            const ushort* wT = (m == 0) ? wqT : (m == 1) ? wkT : wvT;
            f32x4 acc[4];
#pragma unroll
            for (int nt = 0; nt < 4; nt++) acc[nt] = (f32x4){0.f, 0.f, 0.f, 0.f};
#pragma unroll
            for (int kf = 0; kf < 4; kf++) {
#pragma unroll
                for (int nt = 0; nt < 4; nt++) {
                    bf16x8 bfr = *(const bf16x8*)(wT + (lr + 16 * nt) * 128 + (8 * g + 32 * kf));
                    acc[nt] = MFMA_B16(afr[kf], bfr, acc[nt]);
                }
            }
#pragma unroll
            for (int nt = 0; nt < 4; nt++) {
                int col = lr + 16 * nt;
                float bv = (m == 2) ? brv[col] : 0.f;
#pragma unroll
                for (int i = 0; i < 4; i++) {
                    int qrow = 128 * h + 16 * w + 4 * g + i;
                    float v = acc[nt][i];
                    if (m == 0) {
                        int ad = 98304 + qrow * 128 + ((2 * col) ^ ((qrow & 7) << 4));
                        *(ushort*)(smem + ad) = f2bf(v * 0.125f);
                    } else if (m == 1) {
                        int ad = qrow * 128 + ((2 * col) ^ ((qrow & 7) << 4));
                        *(ushort*)(smem + ad) = f2bf(v);
                    } else {
                        int ad = 32768 + col * 512 + ((2 * qrow) ^ ((col & 7) << 4));
                        *(ushort*)(smem + ad) = f2bf(v + bv);
                    }
                }
            }
        }
    }
    __syncthreads();

    bf16x8 qf[2][2];
#pragma unroll
    for (int mt = 0; mt < 2; mt++)
#pragma unroll
        for (int kf = 0; kf < 2; kf++) {
            int qrow = 32 * w + 16 * mt + lr;
            int ab = 98304 + qrow * 128 + ((16 * g + 64 * kf) ^ ((qrow & 7) << 4));
            qf[mt][kf] = *(const bf16x8*)(smem + ab);
        }
    __syncthreads();

    float m_run[2][4], l_run[2][4];
    f32x4 oacc[2][4];
#pragma unroll
    for (int mt = 0; mt < 2; mt++)
#pragma unroll
        for (int i = 0; i < 4; i++) { m_run[mt][i] = -INFINITY; l_run[mt][i] = 0.f; }
#pragma unroll
    for (int mt = 0; mt < 2; mt++)
#pragma unroll
        for (int nt = 0; nt < 4; nt++) oacc[mt][nt] = (f32x4){0.f, 0.f, 0.f, 0.f};

    for (int t = 0; t < 2; t++) {
        f32x4 sacc[2][8];
#pragma unroll
        for (int mt = 0; mt < 2; mt++)
#pragma unroll
            for (int nt = 0; nt < 8; nt++) sacc[mt][nt] = (f32x4){0.f, 0.f, 0.f, 0.f};
#pragma unroll
        for (int nt = 0; nt < 8; nt++) {
#pragma unroll
            for (int kf = 0; kf < 2; kf++) {
                int key = 128 * t + 16 * nt + lr;
                int ab = key * 128 + ((16 * g + 64 * kf) ^ ((key & 7) << 4));
                bf16x8 bfr = *(const bf16x8*)(smem + ab);
#pragma unroll
                for (int mt = 0; mt < 2; mt++)
                    sacc[mt][nt] = MFMA_B16(qf[mt][kf], bfr, sacc[mt][nt]);
            }
        }
#pragma unroll
        for (int mt = 0; mt < 2; mt++) {
#pragma unroll
            for (int i = 0; i < 4; i++) {
                float mx = sacc[mt][0][i];
#pragma unroll
                for (int nt = 1; nt < 8; nt++) mx = fmaxf(mx, sacc[mt][nt][i]);
#pragma unroll
                for (int off = 1; off < 16; off <<= 1) mx = fmaxf(mx, __shfl_xor(mx, off));
                float mnew = fmaxf(m_run[mt][i], mx);
                float corr = __expf(m_run[mt][i] - mnew);
                m_run[mt][i] = mnew;
                int qrow = 32 * w + 16 * mt + 4 * g + i;
                int swq = (qrow & 7) << 4;
                float rs = 0.f;
#pragma unroll
                for (int nt = 0; nt < 8; nt++) {
                    float p = __expf(sacc[mt][nt][i] - mnew);
                    rs += p;
                    int col = lr + 16 * nt;
                    *(ushort*)(smem + 65536 + qrow * 256 + ((2 * col) ^ swq)) = f2bf(p);
                }
#pragma unroll
                for (int off = 1; off < 16; off <<= 1) rs += __shfl_xor(rs, off);
                l_run[mt][i] = l_run[mt][i] * corr + rs;
#pragma unroll
                for (int nt = 0; nt < 4; nt++) oacc[mt][nt][i] *= corr;
            }
        }
        asm volatile("s_waitcnt lgkmcnt(0)" ::: "memory");

#pragma unroll
        for (int kf = 0; kf < 4; kf++) {
            bf16x8 pfr[2];
#pragma unroll
            for (int mt = 0; mt < 2; mt++) {
                int qrow = 32 * w + 16 * mt + lr;
                int ab = 65536 + qrow * 256 + ((16 * g + 64 * kf) ^ ((qrow & 7) << 4));
                pfr[mt] = *(const bf16x8*)(smem + ab);
            }
#pragma unroll
            for (int nt = 0; nt < 4; nt++) {
                int d = lr + 16 * nt;
                int bb = 32768 + d * 512 + ((16 * g + 64 * kf + 256 * t) ^ ((d & 7) << 4));
                bf16x8 bfr = *(const bf16x8*)(smem + bb);
#pragma unroll
                for (int mt = 0; mt < 2; mt++)
                    oacc[mt][nt] = MFMA_B16(pfr[mt], bfr, oacc[mt][nt]);
            }
        }
    }
    __syncthreads();

#pragma unroll
    for (int mt = 0; mt < 2; mt++)
#pragma unroll
        for (int i = 0; i < 4; i++) {
            float rl = 1.0f / l_run[mt][i];
            int qrow = 32 * w + 16 * mt + 4 * g + i;
            int swq = (qrow & 7) << 4;
#pragma unroll
            for (int nt = 0; nt < 4; nt++) {
                int col = lr + 16 * nt;
                *(ushort*)(smem + 65536 + qrow * 128 + ((2 * col) ^ swq)) = f2bf(oacc[mt][nt][i] * rl);
            }
        }
    for (int e = tid; e < 8192; e += 512) {
        int k = e >> 7, c = e & 127;
        int ad = c * 128 + ((2 * k) ^ ((c & 7) << 4));
        *(ushort*)(smem + ad) = f2bf(Wro[e]);
    }
    __syncthreads();

#pragma unroll
    for (int mt = 0; mt < 2; mt++) {
        bf16x8 ofr[2];
#pragma unroll
        for (int kf = 0; kf < 2; kf++) {
            int orow = 32 * w + 16 * mt + lr;
            int ab = 65536 + orow * 128 + ((16 * g + 64 * kf) ^ ((orow & 7) << 4));
            ofr[kf] = *(const bf16x8*)(smem + ab);
        }
#pragma unroll
        for (int nt = 0; nt < 8; nt++) {
            f32x4 acc = (f32x4){0.f, 0.f, 0.f, 0.f};
#pragma unroll
            for (int kf = 0; kf < 2; kf++) {
                int c = lr + 16 * nt;
                int bb = c * 128 + ((16 * g + 64 * kf) ^ ((c & 7) << 4));
                bf16x8 bfr = *(const bf16x8*)(smem + bb);
                acc = MFMA_B16(ofr[kf], bfr, acc);
            }
            int col = lr + 16 * nt;
            float brod = bro[col];
#pragma unroll
            for (int i = 0; i < 4; i++) {
                int qrow = 32 * w + 16 * mt + 4 * g + i;
                size_t off = base + (size_t)qrow * 128 + col;
                x[off] = x[off] + acc[i] + brod;
            }
        }
    }
}

// ---------------------------------------------------------------------------
// F (MFMA MLP v2): 64 rows/block, 2048 blocks, 256 threads (4 waves).
// x += relu(LN(x)@W1+b1)@W2 + b2.  H=256 split into two halves of 128.
// LDS 32 KB: yn [64][128] bf16 @0, h [64][128] bf16 @16384 (row-swz).
// Wave w owns rows [16w, 16w+16) = one M-tile. x kept in registers; delta
// bounced bf16 through yn (dead after A-frag load) -> coalesced f32 store.
// ---------------------------------------------------------------------------
__global__ __launch_bounds__(256, 4) void k_mlp_mfma(
    float* __restrict__ x,
    const float* __restrict__ mn_g, const float* __restrict__ mn_b,
    const ushort* __restrict__ w1T, const ushort* __restrict__ w2T,
    const float* __restrict__ b1, const float* __restrict__ b2)
{
    __shared__ __align__(16) unsigned char smem[32768];
    int tid = threadIdx.x;
    int w = tid >> 6, l = tid & 63;
    int g = l >> 4, lr = l & 15;
    size_t rbase = (size_t)blockIdx.x * 64;

    float xv0[16], xv1[16];

    // ---- LN: wave w -> rows 16w..16w+15, 4-deep load batching
    {
        float gl0 = mn_g[l], gl1 = mn_g[l + 64];
        float el0 = mn_b[l], el1 = mn_b[l + 64];
#pragma unroll
        for (int bb = 0; bb < 4; bb++) {
            float a0[4], a1[4];
#pragma unroll
            for (int rr = 0; rr < 4; rr++) {
                size_t ro = (rbase + 16 * w + 4 * bb + rr) * 128;
                a0[rr] = x[ro + l];
                a1[rr] = x[ro + l + 64];
            }
#pragma unroll
            for (int rr = 0; rr < 4; rr++) {
                int rloc = 16 * w + 4 * bb + rr;
                float x0 = a0[rr], x1 = a1[rr];
                xv0[4 * bb + rr] = x0; xv1[4 * bb + rr] = x1;
                float s = x0 + x1, q = x0 * x0 + x1 * x1;
#pragma unroll
                for (int off = 32; off; off >>= 1) { s += __shfl_xor(s, off); q += __shfl_xor(q, off); }
                float mu = s * (1.0f / 128.0f);
                float var = q * (1.0f / 128.0f) - mu * mu;
                float rs = rsqrtf(var + 1e-5f);
                int sw = (rloc & 7) << 4;
                *(ushort*)(smem + rloc * 256 + ((2 * l) ^ sw))        = f2bf((x0 - mu) * rs * gl0 + el0);
                *(ushort*)(smem + rloc * 256 + ((2 * (l + 64)) ^ sw)) = f2bf((x1 - mu) * rs * gl1 + el1);
            }
        }
    }
    __syncthreads();

    // ---- A-frags of yn (row 16w+lr), persistent across both halves
    bf16x8 afr[4];
#pragma unroll
    for (int kf = 0; kf < 4; kf++) {
        int row = 16 * w + lr;
        afr[kf] = *(const bf16x8*)(smem + row * 256 + ((16 * g + 64 * kf) ^ ((row & 7) << 4)));
    }
    __syncthreads();   // yn consumed into regs by all waves (wave-local rows, but keep it clean)

    f32x4 oacc[8];
#pragma unroll
    for (int nt = 0; nt < 8; nt++) oacc[nt] = (f32x4){0.f, 0.f, 0.f, 0.f};

    for (int kb = 0; kb < 2; kb++) {
        // ---- stage 1: h = relu(yn @ W1[:,128kb:+128] + b1half)
#pragma unroll
        for (int nt = 0; nt < 8; nt++) {
            f32x4 acc = (f32x4){0.f, 0.f, 0.f, 0.f};
#pragma unroll
            for (int kf = 0; kf < 4; kf++) {
                bf16x8 bfr = *(const bf16x8*)(w1T + (size_t)(128 * kb + 16 * nt + lr) * 128 + (32 * kf + 8 * g));
                acc = MFMA_B16(afr[kf], bfr, acc);
            }
            int col = 16 * nt + lr;
            float bb = b1[128 * kb + col];
#pragma unroll
            for (int i = 0; i < 4; i++) {
                int row = 16 * w + 4 * g + i;
                int ad = 16384 + row * 256 + ((2 * col) ^ ((row & 7) << 4));
                *(ushort*)(smem + ad) = f2bf(fmaxf(acc[i] + bb, 0.f));
            }
        }
        __syncthreads();   // h ready

        // ---- stage 2: oacc += h @ W2[128kb:+128, :]
        {
            bf16x8 hfr[4];
#pragma unroll
            for (int kf = 0; kf < 4; kf++) {
                int row = 16 * w + lr;
                hfr[kf] = *(const bf16x8*)(smem + 16384 + row * 256 + ((16 * g + 64 * kf) ^ ((row & 7) << 4)));
            }
#pragma unroll
            for (int nt = 0; nt < 8; nt++) {
#pragma unroll
                for (int kf = 0; kf < 4; kf++) {
                    bf16x8 bfr = *(const bf16x8*)(w2T + (size_t)(16 * nt + lr) * 256 + (128 * kb + 32 * kf + 8 * g));
                    oacc[nt] = MFMA_B16(hfr[kf], bfr, oacc[nt]);
                }
            }
        }
        __syncthreads();   // h consumed; safe to overwrite next half
    }

    // ---- epilogue: bounce delta (bf16) through yn region, add to reg x, store
#pragma unroll
    for (int nt = 0; nt < 8; nt++) {
        int col = 16 * nt + lr;
#pragma unroll
        for (int i = 0; i < 4; i++) {
            int row = 16 * w + 4 * g + i;
            int ad = row * 256 + ((2 * col) ^ ((row & 7) << 4));
            *(ushort*)(smem + ad) = f2bf(oacc[nt][i]);
        }
    }
    asm volatile("s_waitcnt lgkmcnt(0)" ::: "memory");   // wave-local RAW (own rows only)
    {
        float b20 = b2[l], b21 = b2[l + 64];
#pragma unroll
        for (int rr = 0; rr < 16; rr++) {
            int rloc = 16 * w + rr;
            int sw = (rloc & 7) << 4;
            float d0 = lbf(*(const ushort*)(smem + rloc * 256 + ((2 * l) ^ sw)));
            float d1 = lbf(*(const ushort*)(smem + rloc * 256 + ((2 * (l + 64)) ^ sw)));
            size_t ro = (rbase + rloc) * 128;
            x[ro + l]      = xv0[rr] + d0 + b20;
            x[ro + l + 64] = xv1[rr] + d1 + b21;
        }
    }
}

// ---------------------------------------------------------------------------
extern "C" void kernel_launch(void* const* d_in, const int* in_sizes, int n_in,
                              void* d_out, int out_size, void* d_ws, size_t ws_size,
                              hipStream_t stream)
{
    const float* seq   = (const float*)d_in[0];
    const float* pair  = (const float*)d_in[1];
    const float* sn_g  = (const float*)d_in[2];
    const float* sn_b  = (const float*)d_in[3];
    const float* Wq    = (const float*)d_in[4];
    const float* Wk    = (const float*)d_in[5];
    const float* Wyq   = (const float*)d_in[6];
    const float* Wyk   = (const float*)d_in[7];
    const float* Wdist = (const float*)d_in[8];
    const float* Wout  = (const float*)d_in[9];
    const float* bout  = (const float*)d_in[10];
    const float* rn_g  = (const float*)d_in[11];
    const float* rn_b  = (const float*)d_in[12];
    const float* Wrq   = (const float*)d_in[13];
    const float* Wrk   = (const float*)d_in[14];
    const float* Wrv   = (const float*)d_in[15];
    const float* brv   = (const float*)d_in[16];
    const float* Wro   = (const float*)d_in[17];
    const float* bro   = (const float*)d_in[18];
    const float* mn_g  = (const float*)d_in[19];
    const float* mn_b  = (const float*)d_in[20];
    const float* W1    = (const float*)d_in[21];
    const float* b1    = (const float*)d_in[22];
    const float* W2    = (const float*)d_in[23];
    const float* b2    = (const float*)d_in[24];
    (void)in_sizes; (void)n_in; (void)out_size; (void)ws_size;

    // ws: ~1.75 MB used
    float*  x2   = (float*)d_ws;          // [2,256,512]  262144 f32
    float*  a2   = x2 + 262144;           // [2,256,128]   65536 f32
    float*  c2   = a2 + 65536;            // [2,256,128]   65536 f32
    float*  wd2  = c2 + 65536;            // [3,128]+pad     512 f32
    ushort* wqT  = (ushort*)(wd2 + 512);  // [64][128] bf16 8192
    ushort* wkT  = wqT + 8192;
    ushort* wvT  = wkT + 8192;
    ushort* w1T  = wvT + 8192;            // [256][128] bf16 32768
    ushort* w2T  = w1T + 32768;           // [128][256] bf16 32768
    float*  xres = (float*)d_out;

    k_ln_pool  <<<512,   256, 0, stream>>>(seq, sn_g, sn_b, x2);
    k_proj     <<<512,   128, 0, stream>>>(x2, Wq, Wk, Wyq, Wyk, Wout, bout, a2, c2);
    k_wd2      <<<1,     128, 0, stream>>>(Wdist, Wout, wd2);
    k_wt       <<<48,    512, 0, stream>>>(Wrq, Wrk, Wrv, wqT, wkT, wvT);
    k_wt12     <<<128,   512, 0, stream>>>(W1, W2, w1T, w2T);
    k_assemble <<<65536, 256, 0, stream>>>(pair, a2, c2, wd2, xres);
    k_attn_mfma<<<512,   512, 0, stream>>>(xres, rn_g, rn_b, wqT, wkT, wvT, brv, Wro, bro);
    k_mlp_mfma <<<2048,  256, 0, stream>>>(xres, mn_g, mn_b, w1T, w2T, b1, b2);
}

// Round 9
// 345.884 us; speedup vs baseline: 1.1789x; 1.1789x over previous
//
#include <hip/hip_runtime.h>
#include <hip/hip_bf16.h>

using bf16 = __hip_bfloat16;
typedef unsigned int uint;
typedef unsigned short ushort;
typedef __attribute__((ext_vector_type(8))) short bf16x8;
typedef __attribute__((ext_vector_type(4))) float f32x4;

// Shapes: B=2, S=512, SD=512, P=256, PD=128, AD=64, H=256
// All global tensors are f32.

__device__ __forceinline__ float bfraw(uint u) { return __uint_as_float(u << 16); }
__device__ __forceinline__ ushort f2bf(float f) {
    bf16 h = __float2bfloat16(f);
    return *reinterpret_cast<ushort*>(&h);
}
__device__ __forceinline__ float lbf(ushort u) { return __uint_as_float(((uint)u) << 16); }

#define MFMA_B16(a, b, c) __builtin_amdgcn_mfma_f32_16x16x32_bf16((a), (b), (c), 0, 0, 0)

// ---------------------------------------------------------------------------
// A: LayerNorm(seq) over SD=512 + avg-pool row pairs -> x2 f32. 512 blocks.
// ---------------------------------------------------------------------------
__global__ __launch_bounds__(256) void k_ln_pool(
    const float* __restrict__ seq, const float* __restrict__ g,
    const float* __restrict__ be, float* __restrict__ x2)
{
    __shared__ float red[4][4];
    int bp = blockIdx.x;
    int t  = threadIdx.x;
    const float* r0 = seq + (size_t)(bp * 2) * 512;
    const float* r1 = r0 + 512;

    float a0 = r0[t], a1 = r0[t + 256];
    float c0 = r1[t], c1 = r1[t + 256];

    float s0 = a0 + a1, q0 = a0 * a0 + a1 * a1;
    float s1 = c0 + c1, q1 = c0 * c0 + c1 * c1;
#pragma unroll
    for (int off = 32; off; off >>= 1) {
        s0 += __shfl_xor(s0, off); q0 += __shfl_xor(q0, off);
        s1 += __shfl_xor(s1, off); q1 += __shfl_xor(q1, off);
    }
    int w = t >> 6, l = t & 63;
    if (l == 0) { red[0][w] = s0; red[1][w] = q0; red[2][w] = s1; red[3][w] = q1; }
    __syncthreads();
    s0 = red[0][0] + red[0][1] + red[0][2] + red[0][3];
    q0 = red[1][0] + red[1][1] + red[1][2] + red[1][3];
    s1 = red[2][0] + red[2][1] + red[2][2] + red[2][3];
    q1 = red[3][0] + red[3][1] + red[3][2] + red[3][3];

    const float inv = 1.0f / 512.0f;
    float mu0 = s0 * inv, var0 = q0 * inv - mu0 * mu0, rs0 = rsqrtf(var0 + 1e-5f);
    float mu1 = s1 * inv, var1 = q1 * inv - mu1 * mu1, rs1 = rsqrtf(var1 + 1e-5f);

    float g0 = g[t], g1 = g[t + 256];
    float e0 = be[t], e1 = be[t + 256];

    float o0 = 0.5f * ((a0 - mu0) * rs0 * g0 + e0 + (c0 - mu1) * rs1 * g0 + e0);
    float o1 = 0.5f * ((a1 - mu0) * rs0 * g1 + e1 + (c1 - mu1) * rs1 * g1 + e1);

    float* xo = x2 + (size_t)bp * 512;
    xo[t] = o0; xo[t + 256] = o1;
}

// ---------------------------------------------------------------------------
// B: A2 = (x@Wq + gelu(x)@Wyq)@Wout + bout ; C2 = (x@Wk + gelu(x)@Wyk)@Wout
// ---------------------------------------------------------------------------
__global__ __launch_bounds__(128) void k_proj(
    const float* __restrict__ x2,
    const float* __restrict__ Wq, const float* __restrict__ Wk,
    const float* __restrict__ Wyq, const float* __restrict__ Wyk,
    const float* __restrict__ Wout, const float* __restrict__ bout,
    float* __restrict__ a2, float* __restrict__ c2)
{
    __shared__ float xr[512], gxr[512], ar[128], cr[128];
    int row = blockIdx.x;
    int t   = threadIdx.x;

    for (int u = t; u < 512; u += 128) {
        float v = x2[(size_t)row * 512 + u];
        xr[u]  = v;
        gxr[u] = 0.5f * v * (1.0f + erff(v * 0.70710678118654752f));
    }
    __syncthreads();

    float a = 0.f, c = 0.f;
    for (int s = 0; s < 512; s++) {
        float xs = xr[s], gs = gxr[s];
        a += xs * Wq[s * 128 + t] + gs * Wyq[s * 128 + t];
        c += xs * Wk[s * 128 + t] + gs * Wyk[s * 128 + t];
    }
    ar[t] = a; cr[t] = c;
    __syncthreads();

    float A = bout[t], C = 0.f;
    for (int u = 0; u < 128; u++) {
        float wv = Wout[u * 128 + t];
        A += ar[u] * wv;
        C += cr[u] * wv;
    }
    a2[(size_t)row * 128 + t] = A;
    c2[(size_t)row * 128 + t] = C;
}

// ---------------------------------------------------------------------------
// W: Wd2 = Wdist(3x128) @ Wout(128x128)
// ---------------------------------------------------------------------------
__global__ __launch_bounds__(128) void k_wd2(
    const float* __restrict__ Wdist, const float* __restrict__ Wout,
    float* __restrict__ wd2)
{
    int t = threadIdx.x;
#pragma unroll
    for (int f = 0; f < 3; f++) {
        float acc = 0.f;
        for (int u = 0; u < 128; u++)
            acc += Wdist[f * 128 + u] * Wout[u * 128 + t];
        wd2[f * 128 + t] = acc;
    }
}

// ---------------------------------------------------------------------------
// WT prep: wT[c][k] (bf16, [64][128]) = W[k][c] (f32, [128][64]) for Wrq/Wrk/Wrv
// ---------------------------------------------------------------------------
__global__ __launch_bounds__(512) void k_wt(
    const float* __restrict__ Wrq, const float* __restrict__ Wrk,
    const float* __restrict__ Wrv, ushort* __restrict__ wqT,
    ushort* __restrict__ wkT, ushort* __restrict__ wvT)
{
    int idx = blockIdx.x * 512 + threadIdx.x;       // 0 .. 3*8192
    int m = idx >> 13;
    int e = idx & 8191;
    int c = e >> 7, k = e & 127;
    const float* W = (m == 0) ? Wrq : (m == 1) ? Wrk : Wrv;
    ushort* T = (m == 0) ? wqT : (m == 1) ? wkT : wvT;
    T[e] = f2bf(W[k * 64 + c]);
}

// ---------------------------------------------------------------------------
// WT prep 2 (MLP): w1T[c][k] = W1[k][c] (c<256,k<128); w2T[c][k] = W2[k][c]
// ---------------------------------------------------------------------------
__global__ __launch_bounds__(512) void k_wt12(
    const float* __restrict__ W1, const float* __restrict__ W2,
    ushort* __restrict__ w1T, ushort* __restrict__ w2T)
{
    int idx = blockIdx.x * 512 + threadIdx.x;   // 0 .. 65536
    if (idx < 32768) {
        int c = idx >> 7, k = idx & 127;        // W1 [128][256] -> w1T [256][128]
        w1T[idx] = f2bf(W1[k * 256 + c]);
    } else {
        int e = idx - 32768;
        int c = e >> 8, k = e & 255;            // W2 [256][128] -> w2T [128][256]
        w2T[e] = f2bf(W2[k * 128 + c]);
    }
}

// ---------------------------------------------------------------------------
// C: x[b,i,j,d] = pair + A2[b,i,d] + C2[b,j,d] + feats(i,j)·Wd2[:,d] -> d_out
// ---------------------------------------------------------------------------
__global__ __launch_bounds__(256) void k_assemble(
    const float* __restrict__ pair, const float* __restrict__ a2,
    const float* __restrict__ c2, const float* __restrict__ wd2,
    float* __restrict__ xout)
{
    size_t idx = (size_t)blockIdx.x * 256 + threadIdx.x;
    int d = (int)(idx & 127);
    size_t r = idx >> 7;
    int j = (int)(r & 255); r >>= 8;
    int i = (int)(r & 255);
    int b = (int)(r >> 8);

    float ds = fabsf((float)(i - j)) * (1.0f / 255.0f);
    float sg = (float)((i > j) - (i < j));
    float ex = __expf(-ds);

    float v = pair[idx]
            + a2[(size_t)(b * 256 + i) * 128 + d]
            + c2[(size_t)(b * 256 + j) * 128 + d]
            + ds * wd2[d] + sg * wd2[128 + d] + ex * wd2[256 + d];
    xout[idx] = v;
}

// ---------------------------------------------------------------------------
// E (MFMA attention): per (b,i) slice [256 rows x 128].  (unchanged, proven)
// ---------------------------------------------------------------------------
__global__ __launch_bounds__(512, 2) void k_attn_mfma(
    float* __restrict__ x,
    const float* __restrict__ rn_g, const float* __restrict__ rn_b,
    const ushort* __restrict__ wqT, const ushort* __restrict__ wkT,
    const ushort* __restrict__ wvT, const float* __restrict__ brv,
    const float* __restrict__ Wro, const float* __restrict__ bro)
{
    __shared__ __align__(16) unsigned char smem[131072];

    int tid = threadIdx.x;
    int w  = tid >> 6;
    int l  = tid & 63;
    int g  = l >> 4;      // 0..3  (k-group)
    int lr = l & 15;      // 0..15 (row/col within tile)
    size_t base = (size_t)blockIdx.x * 32768;

    float gl0 = rn_g[l], gl1 = rn_g[l + 64];
    float el0 = rn_b[l], el1 = rn_b[l + 64];

    // ================= QKV (two halves of 128 rows) =================
    for (int h = 0; h < 2; h++) {
        for (int rr = 0; rr < 16; rr++) {
            int rloc = 16 * w + rr;
            size_t ro = base + (size_t)(128 * h + rloc) * 128;
            float x0 = x[ro + l], x1 = x[ro + l + 64];
            float s = x0 + x1, q = x0 * x0 + x1 * x1;
#pragma unroll
            for (int off = 32; off; off >>= 1) { s += __shfl_xor(s, off); q += __shfl_xor(q, off); }
            float mu = s * (1.0f / 128.0f);
            float var = q * (1.0f / 128.0f) - mu * mu;
            float rs = rsqrtf(var + 1e-5f);
            int sw = (rloc & 7) << 4;
            *(ushort*)(smem + 65536 + rloc * 256 + ((2 * l) ^ sw))        = f2bf((x0 - mu) * rs * gl0 + el0);
            *(ushort*)(smem + 65536 + rloc * 256 + ((2 * (l + 64)) ^ sw)) = f2bf((x1 - mu) * rs * gl1 + el1);
        }
        asm volatile("s_waitcnt lgkmcnt(0)" ::: "memory");

        bf16x8 afr[4];
        int arow = 16 * w + lr;
#pragma unroll
        for (int kf = 0; kf < 4; kf++) {
            int ab = 65536 + arow * 256 + ((16 * g + 64 * kf) ^ ((arow & 7) << 4));
            afr[kf] = *(const bf16x8*)(smem + ab);
        }
#pragma unroll
        for (int m = 0; m < 3; m++) {
            const ushort* wT = (m == 0) ? wqT : (m == 1) ? wkT : wvT;
            f32x4 acc[4];
#pragma unroll
            for (int nt = 0; nt < 4; nt++) acc[nt] = (f32x4){0.f, 0.f, 0.f, 0.f};
#pragma unroll
            for (int kf = 0; kf < 4; kf++) {
#pragma unroll
                for (int nt = 0; nt < 4; nt++) {
                    bf16x8 bfr = *(const bf16x8*)(wT + (lr + 16 * nt) * 128 + (8 * g + 32 * kf));
                    acc[nt] = MFMA_B16(afr[kf], bfr, acc[nt]);
                }
            }
#pragma unroll
            for (int nt = 0; nt < 4; nt++) {
                int col = lr + 16 * nt;
                float bv = (m == 2) ? brv[col] : 0.f;
#pragma unroll
                for (int i = 0; i < 4; i++) {
                    int qrow = 128 * h + 16 * w + 4 * g + i;
                    float v = acc[nt][i];
                    if (m == 0) {
                        int ad = 98304 + qrow * 128 + ((2 * col) ^ ((qrow & 7) << 4));
                        *(ushort*)(smem + ad) = f2bf(v * 0.125f);
                    } else if (m == 1) {
                        int ad = qrow * 128 + ((2 * col) ^ ((qrow & 7) << 4));
                        *(ushort*)(smem + ad) = f2bf(v);
                    } else {
                        int ad = 32768 + col * 512 + ((2 * qrow) ^ ((col & 7) << 4));
                        *(ushort*)(smem + ad) = f2bf(v + bv);
                    }
                }
            }
        }
    }
    __syncthreads();

    bf16x8 qf[2][2];
#pragma unroll
    for (int mt = 0; mt < 2; mt++)
#pragma unroll
        for (int kf = 0; kf < 2; kf++) {
            int qrow = 32 * w + 16 * mt + lr;
            int ab = 98304 + qrow * 128 + ((16 * g + 64 * kf) ^ ((qrow & 7) << 4));
            qf[mt][kf] = *(const bf16x8*)(smem + ab);
        }
    __syncthreads();

    float m_run[2][4], l_run[2][4];
    f32x4 oacc[2][4];
#pragma unroll
    for (int mt = 0; mt < 2; mt++)
#pragma unroll
        for (int i = 0; i < 4; i++) { m_run[mt][i] = -INFINITY; l_run[mt][i] = 0.f; }
#pragma unroll
    for (int mt = 0; mt < 2; mt++)
#pragma unroll
        for (int nt = 0; nt < 4; nt++) oacc[mt][nt] = (f32x4){0.f, 0.f, 0.f, 0.f};

    for (int t = 0; t < 2; t++) {
        f32x4 sacc[2][8];
#pragma unroll
        for (int mt = 0; mt < 2; mt++)
#pragma unroll
            for (int nt = 0; nt < 8; nt++) sacc[mt][nt] = (f32x4){0.f, 0.f, 0.f, 0.f};
#pragma unroll
        for (int nt = 0; nt < 8; nt++) {
#pragma unroll
            for (int kf = 0; kf < 2; kf++) {
                int key = 128 * t + 16 * nt + lr;
                int ab = key * 128 + ((16 * g + 64 * kf) ^ ((key & 7) << 4));
                bf16x8 bfr = *(const bf16x8*)(smem + ab);
#pragma unroll
                for (int mt = 0; mt < 2; mt++)
                    sacc[mt][nt] = MFMA_B16(qf[mt][kf], bfr, sacc[mt][nt]);
            }
        }
#pragma unroll
        for (int mt = 0; mt < 2; mt++) {
#pragma unroll
            for (int i = 0; i < 4; i++) {
                float mx = sacc[mt][0][i];
#pragma unroll
                for (int nt = 1; nt < 8; nt++) mx = fmaxf(mx, sacc[mt][nt][i]);
#pragma unroll
                for (int off = 1; off < 16; off <<= 1) mx = fmaxf(mx, __shfl_xor(mx, off));
                float mnew = fmaxf(m_run[mt][i], mx);
                float corr = __expf(m_run[mt][i] - mnew);
                m_run[mt][i] = mnew;
                int qrow = 32 * w + 16 * mt + 4 * g + i;
                int swq = (qrow & 7) << 4;
                float rs = 0.f;
#pragma unroll
                for (int nt = 0; nt < 8; nt++) {
                    float p = __expf(sacc[mt][nt][i] - mnew);
                    rs += p;
                    int col = lr + 16 * nt;
                    *(ushort*)(smem + 65536 + qrow * 256 + ((2 * col) ^ swq)) = f2bf(p);
                }
#pragma unroll
                for (int off = 1; off < 16; off <<= 1) rs += __shfl_xor(rs, off);
                l_run[mt][i] = l_run[mt][i] * corr + rs;
#pragma unroll
                for (int nt = 0; nt < 4; nt++) oacc[mt][nt][i] *= corr;
            }
        }
        asm volatile("s_waitcnt lgkmcnt(0)" ::: "memory");

#pragma unroll
        for (int kf = 0; kf < 4; kf++) {
            bf16x8 pfr[2];
#pragma unroll
            for (int mt = 0; mt < 2; mt++) {
                int qrow = 32 * w + 16 * mt + lr;
                int ab = 65536 + qrow * 256 + ((16 * g + 64 * kf) ^ ((qrow & 7) << 4));
                pfr[mt] = *(const bf16x8*)(smem + ab);
            }
#pragma unroll
            for (int nt = 0; nt < 4; nt++) {
                int d = lr + 16 * nt;
                int bb = 32768 + d * 512 + ((16 * g + 64 * kf + 256 * t) ^ ((d & 7) << 4));
                bf16x8 bfr = *(const bf16x8*)(smem + bb);
#pragma unroll
                for (int mt = 0; mt < 2; mt++)
                    oacc[mt][nt] = MFMA_B16(pfr[mt], bfr, oacc[mt][nt]);
            }
        }
    }
    __syncthreads();

#pragma unroll
    for (int mt = 0; mt < 2; mt++)
#pragma unroll
        for (int i = 0; i < 4; i++) {
            float rl = 1.0f / l_run[mt][i];
            int qrow = 32 * w + 16 * mt + 4 * g + i;
            int swq = (qrow & 7) << 4;
#pragma unroll
            for (int nt = 0; nt < 4; nt++) {
                int col = lr + 16 * nt;
                *(ushort*)(smem + 65536 + qrow * 128 + ((2 * col) ^ swq)) = f2bf(oacc[mt][nt][i] * rl);
            }
        }
    for (int e = tid; e < 8192; e += 512) {
        int k = e >> 7, c = e & 127;
        int ad = c * 128 + ((2 * k) ^ ((c & 7) << 4));
        *(ushort*)(smem + ad) = f2bf(Wro[e]);
    }
    __syncthreads();

#pragma unroll
    for (int mt = 0; mt < 2; mt++) {
        bf16x8 ofr[2];
#pragma unroll
        for (int kf = 0; kf < 2; kf++) {
            int orow = 32 * w + 16 * mt + lr;
            int ab = 65536 + orow * 128 + ((16 * g + 64 * kf) ^ ((orow & 7) << 4));
            ofr[kf] = *(const bf16x8*)(smem + ab);
        }
#pragma unroll
        for (int nt = 0; nt < 8; nt++) {
            f32x4 acc = (f32x4){0.f, 0.f, 0.f, 0.f};
#pragma unroll
            for (int kf = 0; kf < 2; kf++) {
                int c = lr + 16 * nt;
                int bb = c * 128 + ((16 * g + 64 * kf) ^ ((c & 7) << 4));
                bf16x8 bfr = *(const bf16x8*)(smem + bb);
                acc = MFMA_B16(ofr[kf], bfr, acc);
            }
            int col = lr + 16 * nt;
            float brod = bro[col];
#pragma unroll
            for (int i = 0; i < 4; i++) {
                int qrow = 32 * w + 16 * mt + 4 * g + i;
                size_t off = base + (size_t)qrow * 128 + col;
                x[off] = x[off] + acc[i] + brod;
            }
        }
    }
}

// ---------------------------------------------------------------------------
// F (MFMA MLP v3): 64 rows/block, 2048 blocks, 256 threads (4 waves).
// x += relu(LN(x)@W1+b1)@W2 + b2.  H=256 split into two halves of 128.
// LDS 32 KB: yn [64][128] bf16 @0, h [64][128] bf16 @16384 (row-swz).
// Wave w owns rows [16w, 16w+16). launch_bounds(256,2): proven no-spill
// (v2's (256,4) forced 64 VGPR + 266MB scratch spill traffic). Epilogue
// bounces delta bf16 through yn region, re-reads x coalesced, stores coalesced.
// ---------------------------------------------------------------------------
__global__ __launch_bounds__(256, 2) void k_mlp_mfma(
    float* __restrict__ x,
    const float* __restrict__ mn_g, const float* __restrict__ mn_b,
    const ushort* __restrict__ w1T, const ushort* __restrict__ w2T,
    const float* __restrict__ b1, const float* __restrict__ b2)
{
    __shared__ __align__(16) unsigned char smem[32768];
    int tid = threadIdx.x;
    int w = tid >> 6, l = tid & 63;
    int g = l >> 4, lr = l & 15;
    size_t rbase = (size_t)blockIdx.x * 64;

    // ---- LN: wave w -> rows 16w..16w+15, 4-deep load batching
    {
        float gl0 = mn_g[l], gl1 = mn_g[l + 64];
        float el0 = mn_b[l], el1 = mn_b[l + 64];
#pragma unroll
        for (int bb = 0; bb < 4; bb++) {
            float a0[4], a1[4];
#pragma unroll
            for (int rr = 0; rr < 4; rr++) {
                size_t ro = (rbase + 16 * w + 4 * bb + rr) * 128;
                a0[rr] = x[ro + l];
                a1[rr] = x[ro + l + 64];
            }
#pragma unroll
            for (int rr = 0; rr < 4; rr++) {
                int rloc = 16 * w + 4 * bb + rr;
                float x0 = a0[rr], x1 = a1[rr];
                float s = x0 + x1, q = x0 * x0 + x1 * x1;
#pragma unroll
                for (int off = 32; off; off >>= 1) { s += __shfl_xor(s, off); q += __shfl_xor(q, off); }
                float mu = s * (1.0f / 128.0f);
                float var = q * (1.0f / 128.0f) - mu * mu;
                float rs = rsqrtf(var + 1e-5f);
                int sw = (rloc & 7) << 4;
                *(ushort*)(smem + rloc * 256 + ((2 * l) ^ sw))        = f2bf((x0 - mu) * rs * gl0 + el0);
                *(ushort*)(smem + rloc * 256 + ((2 * (l + 64)) ^ sw)) = f2bf((x1 - mu) * rs * gl1 + el1);
            }
        }
    }
    __syncthreads();

    // ---- A-frags of yn (row 16w+lr), persistent across both halves
    bf16x8 afr[4];
#pragma unroll
    for (int kf = 0; kf < 4; kf++) {
        int row = 16 * w + lr;
        afr[kf] = *(const bf16x8*)(smem + row * 256 + ((16 * g + 64 * kf) ^ ((row & 7) << 4)));
    }

    f32x4 oacc[8];
#pragma unroll
    for (int nt = 0; nt < 8; nt++) oacc[nt] = (f32x4){0.f, 0.f, 0.f, 0.f};

    for (int kb = 0; kb < 2; kb++) {
        // ---- stage 1: h = relu(yn @ W1[:,128kb:+128] + b1half)
#pragma unroll
        for (int nt = 0; nt < 8; nt++) {
            f32x4 acc = (f32x4){0.f, 0.f, 0.f, 0.f};
#pragma unroll
            for (int kf = 0; kf < 4; kf++) {
                bf16x8 bfr = *(const bf16x8*)(w1T + (size_t)(128 * kb + 16 * nt + lr) * 128 + (32 * kf + 8 * g));
                acc = MFMA_B16(afr[kf], bfr, acc);
            }
            int col = 16 * nt + lr;
            float bb = b1[128 * kb + col];
#pragma unroll
            for (int i = 0; i < 4; i++) {
                int row = 16 * w + 4 * g + i;
                int ad = 16384 + row * 256 + ((2 * col) ^ ((row & 7) << 4));
                *(ushort*)(smem + ad) = f2bf(fmaxf(acc[i] + bb, 0.f));
            }
        }
        __syncthreads();   // h ready

        // ---- stage 2: oacc += h @ W2[128kb:+128, :]
        {
            bf16x8 hfr[4];
#pragma unroll
            for (int kf = 0; kf < 4; kf++) {
                int row = 16 * w + lr;
                hfr[kf] = *(const bf16x8*)(smem + 16384 + row * 256 + ((16 * g + 64 * kf) ^ ((row & 7) << 4)));
            }
#pragma unroll
            for (int nt = 0; nt < 8; nt++) {
#pragma unroll
                for (int kf = 0; kf < 4; kf++) {
                    bf16x8 bfr = *(const bf16x8*)(w2T + (size_t)(16 * nt + lr) * 256 + (128 * kb + 32 * kf + 8 * g));
                    oacc[nt] = MFMA_B16(hfr[kf], bfr, oacc[nt]);
                }
            }
        }
        __syncthreads();   // h consumed; safe to overwrite next half
    }

    // ---- epilogue: bounce delta (bf16) through yn region -> coalesced store
#pragma unroll
    for (int nt = 0; nt < 8; nt++) {
        int col = 16 * nt + lr;
#pragma unroll
        for (int i = 0; i < 4; i++) {
            int row = 16 * w + 4 * g + i;
            int ad = row * 256 + ((2 * col) ^ ((row & 7) << 4));
            *(ushort*)(smem + ad) = f2bf(oacc[nt][i]);
        }
    }
    asm volatile("s_waitcnt lgkmcnt(0)" ::: "memory");   // wave-local RAW (own rows only)
    {
        float b20 = b2[l], b21 = b2[l + 64];
#pragma unroll
        for (int rr = 0; rr < 16; rr++) {
            int rloc = 16 * w + rr;
            int sw = (rloc & 7) << 4;
            float d0 = lbf(*(const ushort*)(smem + rloc * 256 + ((2 * l) ^ sw)));
            float d1 = lbf(*(const ushort*)(smem + rloc * 256 + ((2 * (l + 64)) ^ sw)));
            size_t ro = (rbase + rloc) * 128;
            x[ro + l]      = x[ro + l]      + d0 + b20;
            x[ro + l + 64] = x[ro + l + 64] + d1 + b21;
        }
    }
}

// ---------------------------------------------------------------------------
extern "C" void kernel_launch(void* const* d_in, const int* in_sizes, int n_in,
                              void* d_out, int out_size, void* d_ws, size_t ws_size,
                              hipStream_t stream)
{
    const float* seq   = (const float*)d_in[0];
    const float* pair  = (const float*)d_in[1];
    const float* sn_g  = (const float*)d_in[2];
    const float* sn_b  = (const float*)d_in[3];
    const float* Wq    = (const float*)d_in[4];
    const float* Wk    = (const float*)d_in[5];
    const float* Wyq   = (const float*)d_in[6];
    const float* Wyk   = (const float*)d_in[7];
    const float* Wdist = (const float*)d_in[8];
    const float* Wout  = (const float*)d_in[9];
    const float* bout  = (const float*)d_in[10];
    const float* rn_g  = (const float*)d_in[11];
    const float* rn_b  = (const float*)d_in[12];
    const float* Wrq   = (const float*)d_in[13];
    const float* Wrk   = (const float*)d_in[14];
    const float* Wrv   = (const float*)d_in[15];
    const float* brv   = (const float*)d_in[16];
    const float* Wro   = (const float*)d_in[17];
    const float* bro   = (const float*)d_in[18];
    const float* mn_g  = (const float*)d_in[19];
    const float* mn_b  = (const float*)d_in[20];
    const float* W1    = (const float*)d_in[21];
    const float* b1    = (const float*)d_in[22];
    const float* W2    = (const float*)d_in[23];
    const float* b2    = (const float*)d_in[24];
    (void)in_sizes; (void)n_in; (void)out_size; (void)ws_size;

    // ws: ~1.75 MB used
    float*  x2   = (float*)d_ws;          // [2,256,512]  262144 f32
    float*  a2   = x2 + 262144;           // [2,256,128]   65536 f32
    float*  c2   = a2 + 65536;            // [2,256,128]   65536 f32
    float*  wd2  = c2 + 65536;            // [3,128]+pad     512 f32
    ushort* wqT  = (ushort*)(wd2 + 512);  // [64][128] bf16 8192
    ushort* wkT  = wqT + 8192;
    ushort* wvT  = wkT + 8192;
    ushort* w1T  = wvT + 8192;            // [256][128] bf16 32768
    ushort* w2T  = w1T + 32768;           // [128][256] bf16 32768
    float*  xres = (float*)d_out;

    k_ln_pool  <<<512,   256, 0, stream>>>(seq, sn_g, sn_b, x2);
    k_proj     <<<512,   128, 0, stream>>>(x2, Wq, Wk, Wyq, Wyk, Wout, bout, a2, c2);
    k_wd2      <<<1,     128, 0, stream>>>(Wdist, Wout, wd2);
    k_wt       <<<48,    512, 0, stream>>>(Wrq, Wrk, Wrv, wqT, wkT, wvT);
    k_wt12     <<<128,   512, 0, stream>>>(W1, W2, w1T, w2T);
    k_assemble <<<65536, 256, 0, stream>>>(pair, a2, c2, wd2, xres);
    k_attn_mfma<<<512,   512, 0, stream>>>(xres, rn_g, rn_b, wqT, wkT, wvT, brv, Wro, bro);
    k_mlp_mfma <<<2048,  256, 0, stream>>>(xres, mn_g, mn_b, w1T, w2T, b1, b2);
}

// Round 10
// 295.509 us; speedup vs baseline: 1.3799x; 1.1705x over previous
//
#include <hip/hip_runtime.h>
#include <hip/hip_bf16.h>

using bf16 = __hip_bfloat16;
typedef unsigned int uint;
typedef unsigned short ushort;
typedef __attribute__((ext_vector_type(8))) short bf16x8;
typedef __attribute__((ext_vector_type(4))) float f32x4;

// Shapes: B=2, S=512, SD=512, P=256, PD=128, AD=64, H=256
// All global tensors are f32.

__device__ __forceinline__ float bfraw(uint u) { return __uint_as_float(u << 16); }
__device__ __forceinline__ ushort f2bf(float f) {
    bf16 h = __float2bfloat16(f);
    return *reinterpret_cast<ushort*>(&h);
}
__device__ __forceinline__ float lbf(ushort u) { return __uint_as_float(((uint)u) << 16); }

#define MFMA_B16(a, b, c) __builtin_amdgcn_mfma_f32_16x16x32_bf16((a), (b), (c), 0, 0, 0)

// ---------------------------------------------------------------------------
// A: LayerNorm(seq) over SD=512 + avg-pool row pairs -> x2 f32. 512 blocks.
// ---------------------------------------------------------------------------
__global__ __launch_bounds__(256) void k_ln_pool(
    const float* __restrict__ seq, const float* __restrict__ g,
    const float* __restrict__ be, float* __restrict__ x2)
{
    __shared__ float red[4][4];
    int bp = blockIdx.x;
    int t  = threadIdx.x;
    const float* r0 = seq + (size_t)(bp * 2) * 512;
    const float* r1 = r0 + 512;

    float a0 = r0[t], a1 = r0[t + 256];
    float c0 = r1[t], c1 = r1[t + 256];

    float s0 = a0 + a1, q0 = a0 * a0 + a1 * a1;
    float s1 = c0 + c1, q1 = c0 * c0 + c1 * c1;
#pragma unroll
    for (int off = 32; off; off >>= 1) {
        s0 += __shfl_xor(s0, off); q0 += __shfl_xor(q0, off);
        s1 += __shfl_xor(s1, off); q1 += __shfl_xor(q1, off);
    }
    int w = t >> 6, l = t & 63;
    if (l == 0) { red[0][w] = s0; red[1][w] = q0; red[2][w] = s1; red[3][w] = q1; }
    __syncthreads();
    s0 = red[0][0] + red[0][1] + red[0][2] + red[0][3];
    q0 = red[1][0] + red[1][1] + red[1][2] + red[1][3];
    s1 = red[2][0] + red[2][1] + red[2][2] + red[2][3];
    q1 = red[3][0] + red[3][1] + red[3][2] + red[3][3];

    const float inv = 1.0f / 512.0f;
    float mu0 = s0 * inv, var0 = q0 * inv - mu0 * mu0, rs0 = rsqrtf(var0 + 1e-5f);
    float mu1 = s1 * inv, var1 = q1 * inv - mu1 * mu1, rs1 = rsqrtf(var1 + 1e-5f);

    float g0 = g[t], g1 = g[t + 256];
    float e0 = be[t], e1 = be[t + 256];

    float o0 = 0.5f * ((a0 - mu0) * rs0 * g0 + e0 + (c0 - mu1) * rs1 * g0 + e0);
    float o1 = 0.5f * ((a1 - mu0) * rs0 * g1 + e1 + (c1 - mu1) * rs1 * g1 + e1);

    float* xo = x2 + (size_t)bp * 512;
    xo[t] = o0; xo[t + 256] = o1;
}

// ---------------------------------------------------------------------------
// B: A2 = (x@Wq + gelu(x)@Wyq)@Wout + bout ; C2 = (x@Wk + gelu(x)@Wyk)@Wout
// ---------------------------------------------------------------------------
__global__ __launch_bounds__(128) void k_proj(
    const float* __restrict__ x2,
    const float* __restrict__ Wq, const float* __restrict__ Wk,
    const float* __restrict__ Wyq, const float* __restrict__ Wyk,
    const float* __restrict__ Wout, const float* __restrict__ bout,
    float* __restrict__ a2, float* __restrict__ c2)
{
    __shared__ float xr[512], gxr[512], ar[128], cr[128];
    int row = blockIdx.x;
    int t   = threadIdx.x;

    for (int u = t; u < 512; u += 128) {
        float v = x2[(size_t)row * 512 + u];
        xr[u]  = v;
        gxr[u] = 0.5f * v * (1.0f + erff(v * 0.70710678118654752f));
    }
    __syncthreads();

    float a = 0.f, c = 0.f;
    for (int s = 0; s < 512; s++) {
        float xs = xr[s], gs = gxr[s];
        a += xs * Wq[s * 128 + t] + gs * Wyq[s * 128 + t];
        c += xs * Wk[s * 128 + t] + gs * Wyk[s * 128 + t];
    }
    ar[t] = a; cr[t] = c;
    __syncthreads();

    float A = bout[t], C = 0.f;
    for (int u = 0; u < 128; u++) {
        float wv = Wout[u * 128 + t];
        A += ar[u] * wv;
        C += cr[u] * wv;
    }
    a2[(size_t)row * 128 + t] = A;
    c2[(size_t)row * 128 + t] = C;
}

// ---------------------------------------------------------------------------
// W: Wd2 = Wdist(3x128) @ Wout(128x128)
// ---------------------------------------------------------------------------
__global__ __launch_bounds__(128) void k_wd2(
    const float* __restrict__ Wdist, const float* __restrict__ Wout,
    float* __restrict__ wd2)
{
    int t = threadIdx.x;
#pragma unroll
    for (int f = 0; f < 3; f++) {
        float acc = 0.f;
        for (int u = 0; u < 128; u++)
            acc += Wdist[f * 128 + u] * Wout[u * 128 + t];
        wd2[f * 128 + t] = acc;
    }
}

// ---------------------------------------------------------------------------
// WT prep (attention QKV, FRAGMENT-ORDER): for frag f=(nt*4+kf), lane l:
// wF[f*512 + l*8 + j] = W[(32kf + 8*(l>>4) + j)*64 + 16nt + (l&15)]
// -> a wave's B-frag load is 64 consecutive 16B chunks (coalesced 1KB).
// ---------------------------------------------------------------------------
__global__ __launch_bounds__(512) void k_wt(
    const float* __restrict__ Wrq, const float* __restrict__ Wrk,
    const float* __restrict__ Wrv, ushort* __restrict__ wqF,
    ushort* __restrict__ wkF, ushort* __restrict__ wvF)
{
    int idx = blockIdx.x * 512 + threadIdx.x;       // 0 .. 3*8192
    int m = idx >> 13;
    int o = idx & 8191;
    int f = o >> 9;            // 0..15
    int l = (o >> 3) & 63;
    int j = o & 7;
    int nt = f >> 2, kf = f & 3;
    const float* W = (m == 0) ? Wrq : (m == 1) ? Wrk : Wrv;
    ushort* T = (m == 0) ? wqF : (m == 1) ? wkF : wvF;
    T[o] = f2bf(W[(32 * kf + 8 * (l >> 4) + j) * 64 + 16 * nt + (l & 15)]);
}

// ---------------------------------------------------------------------------
// WT prep 2 (MLP, FRAGMENT-ORDER): frag f=((kb*8+nt)*4+kf), lane l:
// w1F[f*512+l*8+j] = W1[(32kf+8*(l>>4)+j)*256 + 128kb+16nt+(l&15)]
// w2F[f*512+l*8+j] = W2[(128kb+32kf+8*(l>>4)+j)*128 + 16nt+(l&15)]
// ---------------------------------------------------------------------------
__global__ __launch_bounds__(512) void k_wt12(
    const float* __restrict__ W1, const float* __restrict__ W2,
    ushort* __restrict__ w1F, ushort* __restrict__ w2F)
{
    int idx = blockIdx.x * 512 + threadIdx.x;   // 0 .. 65536
    int o = idx & 32767;
    int f = o >> 9;            // 0..63
    int l = (o >> 3) & 63;
    int j = o & 7;
    int kb = f >> 5, nt = (f >> 2) & 7, kf = f & 3;
    if (idx < 32768) {
        int R = 128 * kb + 16 * nt + (l & 15);      // H index   [0,256)
        int C = 32 * kf + 8 * (l >> 4) + j;         // K=PD idx  [0,128)
        w1F[o] = f2bf(W1[C * 256 + R]);
    } else {
        int R2 = 16 * nt + (l & 15);                // PD index  [0,128)
        int C2 = 128 * kb + 32 * kf + 8 * (l >> 4) + j;  // K=H [0,256)
        w2F[o] = f2bf(W2[C2 * 128 + R2]);
    }
}

// ---------------------------------------------------------------------------
// C: x[b,i,j,d] = pair + A2[b,i,d] + C2[b,j,d] + feats(i,j)·Wd2[:,d] -> d_out
// ---------------------------------------------------------------------------
__global__ __launch_bounds__(256) void k_assemble(
    const float* __restrict__ pair, const float* __restrict__ a2,
    const float* __restrict__ c2, const float* __restrict__ wd2,
    float* __restrict__ xout)
{
    size_t idx = (size_t)blockIdx.x * 256 + threadIdx.x;
    int d = (int)(idx & 127);
    size_t r = idx >> 7;
    int j = (int)(r & 255); r >>= 8;
    int i = (int)(r & 255);
    int b = (int)(r >> 8);

    float ds = fabsf((float)(i - j)) * (1.0f / 255.0f);
    float sg = (float)((i > j) - (i < j));
    float ex = __expf(-ds);

    float v = pair[idx]
            + a2[(size_t)(b * 256 + i) * 128 + d]
            + c2[(size_t)(b * 256 + j) * 128 + d]
            + ds * wd2[d] + sg * wd2[128 + d] + ex * wd2[256 + d];
    xout[idx] = v;
}

// ---------------------------------------------------------------------------
// E (MFMA attention): per (b,i) slice [256 rows x 128].
// QKV B-frags now from fragment-ordered wqF/wkF/wvF (coalesced 1KB loads).
// ---------------------------------------------------------------------------
__global__ __launch_bounds__(512, 2) void k_attn_mfma(
    float* __restrict__ x,
    const float* __restrict__ rn_g, const float* __restrict__ rn_b,
    const ushort* __restrict__ wqF, const ushort* __restrict__ wkF,
    const ushort* __restrict__ wvF, const float* __restrict__ brv,
    const float* __restrict__ Wro, const float* __restrict__ bro)
{
    __shared__ __align__(16) unsigned char smem[131072];

    int tid = threadIdx.x;
    int w  = tid >> 6;
    int l  = tid & 63;
    int g  = l >> 4;      // 0..3  (k-group)
    int lr = l & 15;      // 0..15 (row/col within tile)
    size_t base = (size_t)blockIdx.x * 32768;

    float gl0 = rn_g[l], gl1 = rn_g[l + 64];
    float el0 = rn_b[l], el1 = rn_b[l + 64];

    // ================= QKV (two halves of 128 rows) =================
    for (int h = 0; h < 2; h++) {
        for (int rr = 0; rr < 16; rr++) {
            int rloc = 16 * w + rr;
            size_t ro = base + (size_t)(128 * h + rloc) * 128;
            float x0 = x[ro + l], x1 = x[ro + l + 64];
            float s = x0 + x1, q = x0 * x0 + x1 * x1;
#pragma unroll
            for (int off = 32; off; off >>= 1) { s += __shfl_xor(s, off); q += __shfl_xor(q, off); }
            float mu = s * (1.0f / 128.0f);
            float var = q * (1.0f / 128.0f) - mu * mu;
            float rs = rsqrtf(var + 1e-5f);
            int sw = (rloc & 7) << 4;
            *(ushort*)(smem + 65536 + rloc * 256 + ((2 * l) ^ sw))        = f2bf((x0 - mu) * rs * gl0 + el0);
            *(ushort*)(smem + 65536 + rloc * 256 + ((2 * (l + 64)) ^ sw)) = f2bf((x1 - mu) * rs * gl1 + el1);
        }
        asm volatile("s_waitcnt lgkmcnt(0)" ::: "memory");

        bf16x8 afr[4];
        int arow = 16 * w + lr;
#pragma unroll
        for (int kf = 0; kf < 4; kf++) {
            int ab = 65536 + arow * 256 + ((16 * g + 64 * kf) ^ ((arow & 7) << 4));
            afr[kf] = *(const bf16x8*)(smem + ab);
        }
#pragma unroll
        for (int m = 0; m < 3; m++) {
            const ushort* wT = (m == 0) ? wqF : (m == 1) ? wkF : wvF;
            f32x4 acc[4];
#pragma unroll
            for (int nt = 0; nt < 4; nt++) acc[nt] = (f32x4){0.f, 0.f, 0.f, 0.f};
#pragma unroll
            for (int kf = 0; kf < 4; kf++) {
#pragma unroll
                for (int nt = 0; nt < 4; nt++) {
                    bf16x8 bfr = *(const bf16x8*)(wT + (((nt << 2) | kf) << 9) + (l << 3));
                    acc[nt] = MFMA_B16(afr[kf], bfr, acc[nt]);
                }
            }
#pragma unroll
            for (int nt = 0; nt < 4; nt++) {
                int col = lr + 16 * nt;
                float bv = (m == 2) ? brv[col] : 0.f;
#pragma unroll
                for (int i = 0; i < 4; i++) {
                    int qrow = 128 * h + 16 * w + 4 * g + i;
                    float v = acc[nt][i];
                    if (m == 0) {
                        int ad = 98304 + qrow * 128 + ((2 * col) ^ ((qrow & 7) << 4));
                        *(ushort*)(smem + ad) = f2bf(v * 0.125f);
                    } else if (m == 1) {
                        int ad = qrow * 128 + ((2 * col) ^ ((qrow & 7) << 4));
                        *(ushort*)(smem + ad) = f2bf(v);
                    } else {
                        int ad = 32768 + col * 512 + ((2 * qrow) ^ ((col & 7) << 4));
                        *(ushort*)(smem + ad) = f2bf(v + bv);
                    }
                }
            }
        }
    }
    __syncthreads();

    bf16x8 qf[2][2];
#pragma unroll
    for (int mt = 0; mt < 2; mt++)
#pragma unroll
        for (int kf = 0; kf < 2; kf++) {
            int qrow = 32 * w + 16 * mt + lr;
            int ab = 98304 + qrow * 128 + ((16 * g + 64 * kf) ^ ((qrow & 7) << 4));
            qf[mt][kf] = *(const bf16x8*)(smem + ab);
        }
    __syncthreads();

    float m_run[2][4], l_run[2][4];
    f32x4 oacc[2][4];
#pragma unroll
    for (int mt = 0; mt < 2; mt++)
#pragma unroll
        for (int i = 0; i < 4; i++) { m_run[mt][i] = -INFINITY; l_run[mt][i] = 0.f; }
#pragma unroll
    for (int mt = 0; mt < 2; mt++)
#pragma unroll
        for (int nt = 0; nt < 4; nt++) oacc[mt][nt] = (f32x4){0.f, 0.f, 0.f, 0.f};

    for (int t = 0; t < 2; t++) {
        f32x4 sacc[2][8];
#pragma unroll
        for (int mt = 0; mt < 2; mt++)
#pragma unroll
            for (int nt = 0; nt < 8; nt++) sacc[mt][nt] = (f32x4){0.f, 0.f, 0.f, 0.f};
#pragma unroll
        for (int nt = 0; nt < 8; nt++) {
#pragma unroll
            for (int kf = 0; kf < 2; kf++) {
                int key = 128 * t + 16 * nt + lr;
                int ab = key * 128 + ((16 * g + 64 * kf) ^ ((key & 7) << 4));
                bf16x8 bfr = *(const bf16x8*)(smem + ab);
#pragma unroll
                for (int mt = 0; mt < 2; mt++)
                    sacc[mt][nt] = MFMA_B16(qf[mt][kf], bfr, sacc[mt][nt]);
            }
        }
#pragma unroll
        for (int mt = 0; mt < 2; mt++) {
#pragma unroll
            for (int i = 0; i < 4; i++) {
                float mx = sacc[mt][0][i];
#pragma unroll
                for (int nt = 1; nt < 8; nt++) mx = fmaxf(mx, sacc[mt][nt][i]);
#pragma unroll
                for (int off = 1; off < 16; off <<= 1) mx = fmaxf(mx, __shfl_xor(mx, off));
                float mnew = fmaxf(m_run[mt][i], mx);
                float corr = __expf(m_run[mt][i] - mnew);
                m_run[mt][i] = mnew;
                int qrow = 32 * w + 16 * mt + 4 * g + i;
                int swq = (qrow & 7) << 4;
                float rs = 0.f;
#pragma unroll
                for (int nt = 0; nt < 8; nt++) {
                    float p = __expf(sacc[mt][nt][i] - mnew);
                    rs += p;
                    int col = lr + 16 * nt;
                    *(ushort*)(smem + 65536 + qrow * 256 + ((2 * col) ^ swq)) = f2bf(p);
                }
#pragma unroll
                for (int off = 1; off < 16; off <<= 1) rs += __shfl_xor(rs, off);
                l_run[mt][i] = l_run[mt][i] * corr + rs;
#pragma unroll
                for (int nt = 0; nt < 4; nt++) oacc[mt][nt][i] *= corr;
            }
        }
        asm volatile("s_waitcnt lgkmcnt(0)" ::: "memory");

#pragma unroll
        for (int kf = 0; kf < 4; kf++) {
            bf16x8 pfr[2];
#pragma unroll
            for (int mt = 0; mt < 2; mt++) {
                int qrow = 32 * w + 16 * mt + lr;
                int ab = 65536 + qrow * 256 + ((16 * g + 64 * kf) ^ ((qrow & 7) << 4));
                pfr[mt] = *(const bf16x8*)(smem + ab);
            }
#pragma unroll
            for (int nt = 0; nt < 4; nt++) {
                int d = lr + 16 * nt;
                int bb = 32768 + d * 512 + ((16 * g + 64 * kf + 256 * t) ^ ((d & 7) << 4));
                bf16x8 bfr = *(const bf16x8*)(smem + bb);
#pragma unroll
                for (int mt = 0; mt < 2; mt++)
                    oacc[mt][nt] = MFMA_B16(pfr[mt], bfr, oacc[mt][nt]);
            }
        }
    }
    __syncthreads();

#pragma unroll
    for (int mt = 0; mt < 2; mt++)
#pragma unroll
        for (int i = 0; i < 4; i++) {
            float rl = 1.0f / l_run[mt][i];
            int qrow = 32 * w + 16 * mt + 4 * g + i;
            int swq = (qrow & 7) << 4;
#pragma unroll
            for (int nt = 0; nt < 4; nt++) {
                int col = lr + 16 * nt;
                *(ushort*)(smem + 65536 + qrow * 128 + ((2 * col) ^ swq)) = f2bf(oacc[mt][nt][i] * rl);
            }
        }
    for (int e = tid; e < 8192; e += 512) {
        int k = e >> 7, c = e & 127;
        int ad = c * 128 + ((2 * k) ^ ((c & 7) << 4));
        *(ushort*)(smem + ad) = f2bf(Wro[e]);
    }
    __syncthreads();

#pragma unroll
    for (int mt = 0; mt < 2; mt++) {
        bf16x8 ofr[2];
#pragma unroll
        for (int kf = 0; kf < 2; kf++) {
            int orow = 32 * w + 16 * mt + lr;
            int ab = 65536 + orow * 128 + ((16 * g + 64 * kf) ^ ((orow & 7) << 4));
            ofr[kf] = *(const bf16x8*)(smem + ab);
        }
#pragma unroll
        for (int nt = 0; nt < 8; nt++) {
            f32x4 acc = (f32x4){0.f, 0.f, 0.f, 0.f};
#pragma unroll
            for (int kf = 0; kf < 2; kf++) {
                int c = lr + 16 * nt;
                int bb = c * 128 + ((16 * g + 64 * kf) ^ ((c & 7) << 4));
                bf16x8 bfr = *(const bf16x8*)(smem + bb);
                acc = MFMA_B16(ofr[kf], bfr, acc);
            }
            int col = lr + 16 * nt;
            float brod = bro[col];
#pragma unroll
            for (int i = 0; i < 4; i++) {
                int qrow = 32 * w + 16 * mt + 4 * g + i;
                size_t off = base + (size_t)qrow * 128 + col;
                x[off] = x[off] + acc[i] + brod;
            }
        }
    }
}

// ---------------------------------------------------------------------------
// F (MFMA MLP v4): 64 rows/block, 2048 blocks, 256 threads (4 waves).
// B-frags from fragment-ordered w1F/w2F (coalesced 1KB wave loads).
// LDS 32 KB: yn [64][128] bf16 @0 (reused for delta), h @16384.
// ---------------------------------------------------------------------------
__global__ __launch_bounds__(256, 2) void k_mlp_mfma(
    float* __restrict__ x,
    const float* __restrict__ mn_g, const float* __restrict__ mn_b,
    const ushort* __restrict__ w1F, const ushort* __restrict__ w2F,
    const float* __restrict__ b1, const float* __restrict__ b2)
{
    __shared__ __align__(16) unsigned char smem[32768];
    int tid = threadIdx.x;
    int w = tid >> 6, l = tid & 63;
    int g = l >> 4, lr = l & 15;
    size_t rbase = (size_t)blockIdx.x * 64;

    // ---- LN: wave w -> rows 16w..16w+15, 4-deep load batching
    {
        float gl0 = mn_g[l], gl1 = mn_g[l + 64];
        float el0 = mn_b[l], el1 = mn_b[l + 64];
#pragma unroll
        for (int bb = 0; bb < 4; bb++) {
            float a0[4], a1[4];
#pragma unroll
            for (int rr = 0; rr < 4; rr++) {
                size_t ro = (rbase + 16 * w + 4 * bb + rr) * 128;
                a0[rr] = x[ro + l];
                a1[rr] = x[ro + l + 64];
            }
#pragma unroll
            for (int rr = 0; rr < 4; rr++) {
                int rloc = 16 * w + 4 * bb + rr;
                float x0 = a0[rr], x1 = a1[rr];
                float s = x0 + x1, q = x0 * x0 + x1 * x1;
#pragma unroll
                for (int off = 32; off; off >>= 1) { s += __shfl_xor(s, off); q += __shfl_xor(q, off); }
                float mu = s * (1.0f / 128.0f);
                float var = q * (1.0f / 128.0f) - mu * mu;
                float rs = rsqrtf(var + 1e-5f);
                int sw = (rloc & 7) << 4;
                *(ushort*)(smem + rloc * 256 + ((2 * l) ^ sw))        = f2bf((x0 - mu) * rs * gl0 + el0);
                *(ushort*)(smem + rloc * 256 + ((2 * (l + 64)) ^ sw)) = f2bf((x1 - mu) * rs * gl1 + el1);
            }
        }
    }
    __syncthreads();

    // ---- A-frags of yn (row 16w+lr), persistent across both halves
    bf16x8 afr[4];
#pragma unroll
    for (int kf = 0; kf < 4; kf++) {
        int row = 16 * w + lr;
        afr[kf] = *(const bf16x8*)(smem + row * 256 + ((16 * g + 64 * kf) ^ ((row & 7) << 4)));
    }

    f32x4 oacc[8];
#pragma unroll
    for (int nt = 0; nt < 8; nt++) oacc[nt] = (f32x4){0.f, 0.f, 0.f, 0.f};

    for (int kb = 0; kb < 2; kb++) {
        // ---- stage 1: h = relu(yn @ W1[:,128kb:+128] + b1half)
#pragma unroll
        for (int nt = 0; nt < 8; nt++) {
            f32x4 acc = (f32x4){0.f, 0.f, 0.f, 0.f};
#pragma unroll
            for (int kf = 0; kf < 4; kf++) {
                bf16x8 bfr = *(const bf16x8*)(w1F + (((((kb << 3) | nt) << 2) | kf) << 9) + (l << 3));
                acc = MFMA_B16(afr[kf], bfr, acc);
            }
            int col = 16 * nt + lr;
            float bb = b1[128 * kb + col];
#pragma unroll
            for (int i = 0; i < 4; i++) {
                int row = 16 * w + 4 * g + i;
                int ad = 16384 + row * 256 + ((2 * col) ^ ((row & 7) << 4));
                *(ushort*)(smem + ad) = f2bf(fmaxf(acc[i] + bb, 0.f));
            }
        }
        __syncthreads();   // h ready

        // ---- stage 2: oacc += h @ W2[128kb:+128, :]
        {
            bf16x8 hfr[4];
#pragma unroll
            for (int kf = 0; kf < 4; kf++) {
                int row = 16 * w + lr;
                hfr[kf] = *(const bf16x8*)(smem + 16384 + row * 256 + ((16 * g + 64 * kf) ^ ((row & 7) << 4)));
            }
#pragma unroll
            for (int nt = 0; nt < 8; nt++) {
#pragma unroll
                for (int kf = 0; kf < 4; kf++) {
                    bf16x8 bfr = *(const bf16x8*)(w2F + (((((kb << 3) | nt) << 2) | kf) << 9) + (l << 3));
                    oacc[nt] = MFMA_B16(hfr[kf], bfr, oacc[nt]);
                }
            }
        }
        __syncthreads();   // h consumed; safe to overwrite next half
    }

    // ---- epilogue: bounce delta (bf16) through yn region -> coalesced store
#pragma unroll
    for (int nt = 0; nt < 8; nt++) {
        int col = 16 * nt + lr;
#pragma unroll
        for (int i = 0; i < 4; i++) {
            int row = 16 * w + 4 * g + i;
            int ad = row * 256 + ((2 * col) ^ ((row & 7) << 4));
            *(ushort*)(smem + ad) = f2bf(oacc[nt][i]);
        }
    }
    asm volatile("s_waitcnt lgkmcnt(0)" ::: "memory");   // wave-local RAW (own rows only)
    {
        float b20 = b2[l], b21 = b2[l + 64];
#pragma unroll
        for (int rr = 0; rr < 16; rr++) {
            int rloc = 16 * w + rr;
            int sw = (rloc & 7) << 4;
            float d0 = lbf(*(const ushort*)(smem + rloc * 256 + ((2 * l) ^ sw)));
            float d1 = lbf(*(const ushort*)(smem + rloc * 256 + ((2 * (l + 64)) ^ sw)));
            size_t ro = (rbase + rloc) * 128;
            x[ro + l]      = x[ro + l]      + d0 + b20;
            x[ro + l + 64] = x[ro + l + 64] + d1 + b21;
        }
    }
}

// ---------------------------------------------------------------------------
extern "C" void kernel_launch(void* const* d_in, const int* in_sizes, int n_in,
                              void* d_out, int out_size, void* d_ws, size_t ws_size,
                              hipStream_t stream)
{
    const float* seq   = (const float*)d_in[0];
    const float* pair  = (const float*)d_in[1];
    const float* sn_g  = (const float*)d_in[2];
    const float* sn_b  = (const float*)d_in[3];
    const float* Wq    = (const float*)d_in[4];
    const float* Wk    = (const float*)d_in[5];
    const float* Wyq   = (const float*)d_in[6];
    const float* Wyk   = (const float*)d_in[7];
    const float* Wdist = (const float*)d_in[8];
    const float* Wout  = (const float*)d_in[9];
    const float* bout  = (const float*)d_in[10];
    const float* rn_g  = (const float*)d_in[11];
    const float* rn_b  = (const float*)d_in[12];
    const float* Wrq   = (const float*)d_in[13];
    const float* Wrk   = (const float*)d_in[14];
    const float* Wrv   = (const float*)d_in[15];
    const float* brv   = (const float*)d_in[16];
    const float* Wro   = (const float*)d_in[17];
    const float* bro   = (const float*)d_in[18];
    const float* mn_g  = (const float*)d_in[19];
    const float* mn_b  = (const float*)d_in[20];
    const float* W1    = (const float*)d_in[21];
    const float* b1    = (const float*)d_in[22];
    const float* W2    = (const float*)d_in[23];
    const float* b2    = (const float*)d_in[24];
    (void)in_sizes; (void)n_in; (void)out_size; (void)ws_size;

    // ws: ~1.75 MB used
    float*  x2   = (float*)d_ws;          // [2,256,512]  262144 f32
    float*  a2   = x2 + 262144;           // [2,256,128]   65536 f32
    float*  c2   = a2 + 65536;            // [2,256,128]   65536 f32
    float*  wd2  = c2 + 65536;            // [3,128]+pad     512 f32
    ushort* wqF  = (ushort*)(wd2 + 512);  // frag-order 8192 each
    ushort* wkF  = wqF + 8192;
    ushort* wvF  = wkF + 8192;
    ushort* w1F  = wvF + 8192;            // frag-order 32768
    ushort* w2F  = w1F + 32768;           // frag-order 32768
    float*  xres = (float*)d_out;

    k_ln_pool  <<<512,   256, 0, stream>>>(seq, sn_g, sn_b, x2);
    k_proj     <<<512,   128, 0, stream>>>(x2, Wq, Wk, Wyq, Wyk, Wout, bout, a2, c2);
    k_wd2      <<<1,     128, 0, stream>>>(Wdist, Wout, wd2);
    k_wt       <<<48,    512, 0, stream>>>(Wrq, Wrk, Wrv, wqF, wkF, wvF);
    k_wt12     <<<128,   512, 0, stream>>>(W1, W2, w1F, w2F);
    k_assemble <<<65536, 256, 0, stream>>>(pair, a2, c2, wd2, xres);
    k_attn_mfma<<<512,   512, 0, stream>>>(xres, rn_g, rn_b, wqF, wkF, wvF, brv, Wro, bro);
    k_mlp_mfma <<<2048,  256, 0, stream>>>(xres, mn_g, mn_b, w1F, w2F, b1, b2);
}

// Round 12
// 242.763 us; speedup vs baseline: 1.6797x; 1.2173x over previous
//
#include <hip/hip_runtime.h>
#include <hip/hip_bf16.h>

using bf16 = __hip_bfloat16;
typedef unsigned int uint;
typedef unsigned short ushort;
typedef __attribute__((ext_vector_type(8))) short bf16x8;
typedef __attribute__((ext_vector_type(4))) float f32x4;

// Shapes: B=2, S=512, SD=512, P=256, PD=128, AD=64, H=256
// All global tensors are f32.

__device__ __forceinline__ float bfraw(uint u) { return __uint_as_float(u << 16); }
__device__ __forceinline__ ushort f2bf(float f) {
    bf16 h = __float2bfloat16(f);
    return *reinterpret_cast<ushort*>(&h);
}
__device__ __forceinline__ float lbf(ushort u) { return __uint_as_float(((uint)u) << 16); }

#define MFMA_B16(a, b, c) __builtin_amdgcn_mfma_f32_16x16x32_bf16((a), (b), (c), 0, 0, 0)

// ---------------------------------------------------------------------------
// A: LayerNorm(seq) over SD=512 + avg-pool row pairs -> x2 f32. 512 blocks.
// ---------------------------------------------------------------------------
__global__ __launch_bounds__(256) void k_ln_pool(
    const float* __restrict__ seq, const float* __restrict__ g,
    const float* __restrict__ be, float* __restrict__ x2)
{
    __shared__ float red[4][4];
    int bp = blockIdx.x;
    int t  = threadIdx.x;
    const float* r0 = seq + (size_t)(bp * 2) * 512;
    const float* r1 = r0 + 512;

    float a0 = r0[t], a1 = r0[t + 256];
    float c0 = r1[t], c1 = r1[t + 256];

    float s0 = a0 + a1, q0 = a0 * a0 + a1 * a1;
    float s1 = c0 + c1, q1 = c0 * c0 + c1 * c1;
#pragma unroll
    for (int off = 32; off; off >>= 1) {
        s0 += __shfl_xor(s0, off); q0 += __shfl_xor(q0, off);
        s1 += __shfl_xor(s1, off); q1 += __shfl_xor(q1, off);
    }
    int w = t >> 6, l = t & 63;
    if (l == 0) { red[0][w] = s0; red[1][w] = q0; red[2][w] = s1; red[3][w] = q1; }
    __syncthreads();
    s0 = red[0][0] + red[0][1] + red[0][2] + red[0][3];
    q0 = red[1][0] + red[1][1] + red[1][2] + red[1][3];
    s1 = red[2][0] + red[2][1] + red[2][2] + red[2][3];
    q1 = red[3][0] + red[3][1] + red[3][2] + red[3][3];

    const float inv = 1.0f / 512.0f;
    float mu0 = s0 * inv, var0 = q0 * inv - mu0 * mu0, rs0 = rsqrtf(var0 + 1e-5f);
    float mu1 = s1 * inv, var1 = q1 * inv - mu1 * mu1, rs1 = rsqrtf(var1 + 1e-5f);

    float g0 = g[t], g1 = g[t + 256];
    float e0 = be[t], e1 = be[t + 256];

    float o0 = 0.5f * ((a0 - mu0) * rs0 * g0 + e0 + (c0 - mu1) * rs1 * g0 + e0);
    float o1 = 0.5f * ((a1 - mu0) * rs0 * g1 + e1 + (c1 - mu1) * rs1 * g1 + e1);

    float* xo = x2 + (size_t)bp * 512;
    xo[t] = o0; xo[t + 256] = o1;
}

// ---------------------------------------------------------------------------
// B: A2 = (x@Wq + gelu(x)@Wyq)@Wout + bout ; C2 = (x@Wk + gelu(x)@Wyk)@Wout
// ---------------------------------------------------------------------------
__global__ __launch_bounds__(128) void k_proj(
    const float* __restrict__ x2,
    const float* __restrict__ Wq, const float* __restrict__ Wk,
    const float* __restrict__ Wyq, const float* __restrict__ Wyk,
    const float* __restrict__ Wout, const float* __restrict__ bout,
    float* __restrict__ a2, float* __restrict__ c2)
{
    __shared__ float xr[512], gxr[512], ar[128], cr[128];
    int row = blockIdx.x;
    int t   = threadIdx.x;

    for (int u = t; u < 512; u += 128) {
        float v = x2[(size_t)row * 512 + u];
        xr[u]  = v;
        gxr[u] = 0.5f * v * (1.0f + erff(v * 0.70710678118654752f));
    }
    __syncthreads();

    float a = 0.f, c = 0.f;
    for (int s = 0; s < 512; s++) {
        float xs = xr[s], gs = gxr[s];
        a += xs * Wq[s * 128 + t] + gs * Wyq[s * 128 + t];
        c += xs * Wk[s * 128 + t] + gs * Wyk[s * 128 + t];
    }
    ar[t] = a; cr[t] = c;
    __syncthreads();

    float A = bout[t], C = 0.f;
    for (int u = 0; u < 128; u++) {
        float wv = Wout[u * 128 + t];
        A += ar[u] * wv;
        C += cr[u] * wv;
    }
    a2[(size_t)row * 128 + t] = A;
    c2[(size_t)row * 128 + t] = C;
}

// ---------------------------------------------------------------------------
// W: Wd2 = Wdist(3x128) @ Wout(128x128)
// ---------------------------------------------------------------------------
__global__ __launch_bounds__(128) void k_wd2(
    const float* __restrict__ Wdist, const float* __restrict__ Wout,
    float* __restrict__ wd2)
{
    int t = threadIdx.x;
#pragma unroll
    for (int f = 0; f < 3; f++) {
        float acc = 0.f;
        for (int u = 0; u < 128; u++)
            acc += Wdist[f * 128 + u] * Wout[u * 128 + t];
        wd2[f * 128 + t] = acc;
    }
}

// ---------------------------------------------------------------------------
// WT prep (attention QKV, FRAGMENT-ORDER): for frag f=(nt*4+kf), lane l:
// wF[f*512 + l*8 + j] = W[(32kf + 8*(l>>4) + j)*64 + 16nt + (l&15)]
// ---------------------------------------------------------------------------
__global__ __launch_bounds__(512) void k_wt(
    const float* __restrict__ Wrq, const float* __restrict__ Wrk,
    const float* __restrict__ Wrv, ushort* __restrict__ wqF,
    ushort* __restrict__ wkF, ushort* __restrict__ wvF)
{
    int idx = blockIdx.x * 512 + threadIdx.x;       // 0 .. 3*8192
    int m = idx >> 13;
    int o = idx & 8191;
    int f = o >> 9;            // 0..15
    int l = (o >> 3) & 63;
    int j = o & 7;
    int nt = f >> 2, kf = f & 3;
    const float* W = (m == 0) ? Wrq : (m == 1) ? Wrk : Wrv;
    ushort* T = (m == 0) ? wqF : (m == 1) ? wkF : wvF;
    T[o] = f2bf(W[(32 * kf + 8 * (l >> 4) + j) * 64 + 16 * nt + (l & 15)]);
}

// ---------------------------------------------------------------------------
// WT prep 2 (MLP, FRAGMENT-ORDER): frag f=((kb*8+nt)*4+kf), lane l:
// w1F[f*512+l*8+j] = W1[(32kf+8*(l>>4)+j)*256 + 128kb+16nt+(l&15)]
// w2F[f*512+l*8+j] = W2[(128kb+32kf+8*(l>>4)+j)*128 + 16nt+(l&15)]
// ---------------------------------------------------------------------------
__global__ __launch_bounds__(512) void k_wt12(
    const float* __restrict__ W1, const float* __restrict__ W2,
    ushort* __restrict__ w1F, ushort* __restrict__ w2F)
{
    int idx = blockIdx.x * 512 + threadIdx.x;   // 0 .. 65536
    int o = idx & 32767;
    int f = o >> 9;            // 0..63
    int l = (o >> 3) & 63;
    int j = o & 7;
    int kb = f >> 5, nt = (f >> 2) & 7, kf = f & 3;
    if (idx < 32768) {
        int R = 128 * kb + 16 * nt + (l & 15);      // H index   [0,256)
        int C = 32 * kf + 8 * (l >> 4) + j;         // K=PD idx  [0,128)
        w1F[o] = f2bf(W1[C * 256 + R]);
    } else {
        int R2 = 16 * nt + (l & 15);                // PD index  [0,128)
        int C2 = 128 * kb + 32 * kf + 8 * (l >> 4) + j;  // K=H [0,256)
        w2F[o] = f2bf(W2[C2 * 128 + R2]);
    }
}

// ---------------------------------------------------------------------------
// C: x[b,i,j,d] = pair + A2[b,i,d] + C2[b,j,d] + feats(i,j)·Wd2[:,d] -> d_out
// ---------------------------------------------------------------------------
__global__ __launch_bounds__(256) void k_assemble(
    const float* __restrict__ pair, const float* __restrict__ a2,
    const float* __restrict__ c2, const float* __restrict__ wd2,
    float* __restrict__ xout)
{
    size_t idx = (size_t)blockIdx.x * 256 + threadIdx.x;
    int d = (int)(idx & 127);
    size_t r = idx >> 7;
    int j = (int)(r & 255); r >>= 8;
    int i = (int)(r & 255);
    int b = (int)(r >> 8);

    float ds = fabsf((float)(i - j)) * (1.0f / 255.0f);
    float sg = (float)((i > j) - (i < j));
    float ex = __expf(-ds);

    float v = pair[idx]
            + a2[(size_t)(b * 256 + i) * 128 + d]
            + c2[(size_t)(b * 256 + j) * 128 + d]
            + ds * wd2[d] + sg * wd2[128 + d] + ex * wd2[256 + d];
    xout[idx] = v;
}

// ---------------------------------------------------------------------------
// E (MFMA attention): per (b,i) slice [256 rows x 128].  (unchanged)
// ---------------------------------------------------------------------------
__global__ __launch_bounds__(512, 2) void k_attn_mfma(
    float* __restrict__ x,
    const float* __restrict__ rn_g, const float* __restrict__ rn_b,
    const ushort* __restrict__ wqF, const ushort* __restrict__ wkF,
    const ushort* __restrict__ wvF, const float* __restrict__ brv,
    const float* __restrict__ Wro, const float* __restrict__ bro)
{
    __shared__ __align__(16) unsigned char smem[131072];

    int tid = threadIdx.x;
    int w  = tid >> 6;
    int l  = tid & 63;
    int g  = l >> 4;      // 0..3  (k-group)
    int lr = l & 15;      // 0..15 (row/col within tile)
    size_t base = (size_t)blockIdx.x * 32768;

    float gl0 = rn_g[l], gl1 = rn_g[l + 64];
    float el0 = rn_b[l], el1 = rn_b[l + 64];

    // ================= QKV (two halves of 128 rows) =================
    for (int h = 0; h < 2; h++) {
        for (int rr = 0; rr < 16; rr++) {
            int rloc = 16 * w + rr;
            size_t ro = base + (size_t)(128 * h + rloc) * 128;
            float x0 = x[ro + l], x1 = x[ro + l + 64];
            float s = x0 + x1, q = x0 * x0 + x1 * x1;
#pragma unroll
            for (int off = 32; off; off >>= 1) { s += __shfl_xor(s, off); q += __shfl_xor(q, off); }
            float mu = s * (1.0f / 128.0f);
            float var = q * (1.0f / 128.0f) - mu * mu;
            float rs = rsqrtf(var + 1e-5f);
            int sw = (rloc & 7) << 4;
            *(ushort*)(smem + 65536 + rloc * 256 + ((2 * l) ^ sw))        = f2bf((x0 - mu) * rs * gl0 + el0);
            *(ushort*)(smem + 65536 + rloc * 256 + ((2 * (l + 64)) ^ sw)) = f2bf((x1 - mu) * rs * gl1 + el1);
        }
        asm volatile("s_waitcnt lgkmcnt(0)" ::: "memory");

        bf16x8 afr[4];
        int arow = 16 * w + lr;
#pragma unroll
        for (int kf = 0; kf < 4; kf++) {
            int ab = 65536 + arow * 256 + ((16 * g + 64 * kf) ^ ((arow & 7) << 4));
            afr[kf] = *(const bf16x8*)(smem + ab);
        }
#pragma unroll
        for (int m = 0; m < 3; m++) {
            const ushort* wT = (m == 0) ? wqF : (m == 1) ? wkF : wvF;
            f32x4 acc[4];
#pragma unroll
            for (int nt = 0; nt < 4; nt++) acc[nt] = (f32x4){0.f, 0.f, 0.f, 0.f};
#pragma unroll
            for (int kf = 0; kf < 4; kf++) {
#pragma unroll
                for (int nt = 0; nt < 4; nt++) {
                    bf16x8 bfr = *(const bf16x8*)(wT + (((nt << 2) | kf) << 9) + (l << 3));
                    acc[nt] = MFMA_B16(afr[kf], bfr, acc[nt]);
                }
            }
#pragma unroll
            for (int nt = 0; nt < 4; nt++) {
                int col = lr + 16 * nt;
                float bv = (m == 2) ? brv[col] : 0.f;
#pragma unroll
                for (int i = 0; i < 4; i++) {
                    int qrow = 128 * h + 16 * w + 4 * g + i;
                    float v = acc[nt][i];
                    if (m == 0) {
                        int ad = 98304 + qrow * 128 + ((2 * col) ^ ((qrow & 7) << 4));
                        *(ushort*)(smem + ad) = f2bf(v * 0.125f);
                    } else if (m == 1) {
                        int ad = qrow * 128 + ((2 * col) ^ ((qrow & 7) << 4));
                        *(ushort*)(smem + ad) = f2bf(v);
                    } else {
                        int ad = 32768 + col * 512 + ((2 * qrow) ^ ((col & 7) << 4));
                        *(ushort*)(smem + ad) = f2bf(v + bv);
                    }
                }
            }
        }
    }
    __syncthreads();

    bf16x8 qf[2][2];
#pragma unroll
    for (int mt = 0; mt < 2; mt++)
#pragma unroll
        for (int kf = 0; kf < 2; kf++) {
            int qrow = 32 * w + 16 * mt + lr;
            int ab = 98304 + qrow * 128 + ((16 * g + 64 * kf) ^ ((qrow & 7) << 4));
            qf[mt][kf] = *(const bf16x8*)(smem + ab);
        }
    __syncthreads();

    float m_run[2][4], l_run[2][4];
    f32x4 oacc[2][4];
#pragma unroll
    for (int mt = 0; mt < 2; mt++)
#pragma unroll
        for (int i = 0; i < 4; i++) { m_run[mt][i] = -INFINITY; l_run[mt][i] = 0.f; }
#pragma unroll
    for (int mt = 0; mt < 2; mt++)
#pragma unroll
        for (int nt = 0; nt < 4; nt++) oacc[mt][nt] = (f32x4){0.f, 0.f, 0.f, 0.f};

    for (int t = 0; t < 2; t++) {
        f32x4 sacc[2][8];
#pragma unroll
        for (int mt = 0; mt < 2; mt++)
#pragma unroll
            for (int nt = 0; nt < 8; nt++) sacc[mt][nt] = (f32x4){0.f, 0.f, 0.f, 0.f};
#pragma unroll
        for (int nt = 0; nt < 8; nt++) {
#pragma unroll
            for (int kf = 0; kf < 2; kf++) {
                int key = 128 * t + 16 * nt + lr;
                int ab = key * 128 + ((16 * g + 64 * kf) ^ ((key & 7) << 4));
                bf16x8 bfr = *(const bf16x8*)(smem + ab);
#pragma unroll
                for (int mt = 0; mt < 2; mt++)
                    sacc[mt][nt] = MFMA_B16(qf[mt][kf], bfr, sacc[mt][nt]);
            }
        }
#pragma unroll
        for (int mt = 0; mt < 2; mt++) {
#pragma unroll
            for (int i = 0; i < 4; i++) {
                float mx = sacc[mt][0][i];
#pragma unroll
                for (int nt = 1; nt < 8; nt++) mx = fmaxf(mx, sacc[mt][nt][i]);
#pragma unroll
                for (int off = 1; off < 16; off <<= 1) mx = fmaxf(mx, __shfl_xor(mx, off));
                float mnew = fmaxf(m_run[mt][i], mx);
                float corr = __expf(m_run[mt][i] - mnew);
                m_run[mt][i] = mnew;
                int qrow = 32 * w + 16 * mt + 4 * g + i;
                int swq = (qrow & 7) << 4;
                float rs = 0.f;
#pragma unroll
                for (int nt = 0; nt < 8; nt++) {
                    float p = __expf(sacc[mt][nt][i] - mnew);
                    rs += p;
                    int col = lr + 16 * nt;
                    *(ushort*)(smem + 65536 + qrow * 256 + ((2 * col) ^ swq)) = f2bf(p);
                }
#pragma unroll
                for (int off = 1; off < 16; off <<= 1) rs += __shfl_xor(rs, off);
                l_run[mt][i] = l_run[mt][i] * corr + rs;
#pragma unroll
                for (int nt = 0; nt < 4; nt++) oacc[mt][nt][i] *= corr;
            }
        }
        asm volatile("s_waitcnt lgkmcnt(0)" ::: "memory");

#pragma unroll
        for (int kf = 0; kf < 4; kf++) {
            bf16x8 pfr[2];
#pragma unroll
            for (int mt = 0; mt < 2; mt++) {
                int qrow = 32 * w + 16 * mt + lr;
                int ab = 65536 + qrow * 256 + ((16 * g + 64 * kf) ^ ((qrow & 7) << 4));
                pfr[mt] = *(const bf16x8*)(smem + ab);
            }
#pragma unroll
            for (int nt = 0; nt < 4; nt++) {
                int d = lr + 16 * nt;
                int bb = 32768 + d * 512 + ((16 * g + 64 * kf + 256 * t) ^ ((d & 7) << 4));
                bf16x8 bfr = *(const bf16x8*)(smem + bb);
#pragma unroll
                for (int mt = 0; mt < 2; mt++)
                    oacc[mt][nt] = MFMA_B16(pfr[mt], bfr, oacc[mt][nt]);
            }
        }
    }
    __syncthreads();

#pragma unroll
    for (int mt = 0; mt < 2; mt++)
#pragma unroll
        for (int i = 0; i < 4; i++) {
            float rl = 1.0f / l_run[mt][i];
            int qrow = 32 * w + 16 * mt + 4 * g + i;
            int swq = (qrow & 7) << 4;
#pragma unroll
            for (int nt = 0; nt < 4; nt++) {
                int col = lr + 16 * nt;
                *(ushort*)(smem + 65536 + qrow * 128 + ((2 * col) ^ swq)) = f2bf(oacc[mt][nt][i] * rl);
            }
        }
    for (int e = tid; e < 8192; e += 512) {
        int k = e >> 7, c = e & 127;
        int ad = c * 128 + ((2 * k) ^ ((c & 7) << 4));
        *(ushort*)(smem + ad) = f2bf(Wro[e]);
    }
    __syncthreads();

#pragma unroll
    for (int mt = 0; mt < 2; mt++) {
        bf16x8 ofr[2];
#pragma unroll
        for (int kf = 0; kf < 2; kf++) {
            int orow = 32 * w + 16 * mt + lr;
            int ab = 65536 + orow * 128 + ((16 * g + 64 * kf) ^ ((orow & 7) << 4));
            ofr[kf] = *(const bf16x8*)(smem + ab);
        }
#pragma unroll
        for (int nt = 0; nt < 8; nt++) {
            f32x4 acc = (f32x4){0.f, 0.f, 0.f, 0.f};
#pragma unroll
            for (int kf = 0; kf < 2; kf++) {
                int c = lr + 16 * nt;
                int bb = c * 128 + ((16 * g + 64 * kf) ^ ((c & 7) << 4));
                bf16x8 bfr = *(const bf16x8*)(smem + bb);
                acc = MFMA_B16(ofr[kf], bfr, acc);
            }
            int col = lr + 16 * nt;
            float brod = bro[col];
#pragma unroll
            for (int i = 0; i < 4; i++) {
                int qrow = 32 * w + 16 * mt + 4 * g + i;
                size_t off = base + (size_t)qrow * 128 + col;
                x[off] = x[off] + acc[i] + brod;
            }
        }
    }
}

// ---------------------------------------------------------------------------
// F (MFMA MLP v6, barrier-free): 16 rows/block, 1 wave/block, 8192 blocks.
// All producer->consumer hops are wave-local LDS bounces (lgkmcnt only).
// Per 32-col H-chunk: 8 MFMA stage1 -> 1KB bounce -> 8 MFMA stage2.
// LDS 5120 B: yn [16][128] bf16 @0 (reused for delta), hscratch [16][32] @4096.
// hscratch swizzle uses (row&3)<<4: 16B-granular (bits>=4 only) so the
// contiguous bf16x8 read matches the write permutation (v5 bug: <<3 flipped
// bit 3 inside the 16B fragment -> half the rows read garbage).
// ---------------------------------------------------------------------------
__global__ __launch_bounds__(64, 4) void k_mlp_mfma(
    float* __restrict__ x,
    const float* __restrict__ mn_g, const float* __restrict__ mn_b,
    const ushort* __restrict__ w1F, const ushort* __restrict__ w2F,
    const float* __restrict__ b1, const float* __restrict__ b2)
{
    __shared__ __align__(16) unsigned char smem[5120];
    int l = threadIdx.x;          // 0..63
    int g = l >> 4, lr = l & 15;
    size_t rbase = (size_t)blockIdx.x * 16;

    // ---- LN: 16 rows, 4-deep load batching, wave-local
    {
        float gl0 = mn_g[l], gl1 = mn_g[l + 64];
        float el0 = mn_b[l], el1 = mn_b[l + 64];
#pragma unroll
        for (int bb = 0; bb < 4; bb++) {
            float a0[4], a1[4];
#pragma unroll
            for (int rr = 0; rr < 4; rr++) {
                size_t ro = (rbase + 4 * bb + rr) * 128;
                a0[rr] = x[ro + l];
                a1[rr] = x[ro + l + 64];
            }
#pragma unroll
            for (int rr = 0; rr < 4; rr++) {
                int rloc = 4 * bb + rr;
                float x0 = a0[rr], x1 = a1[rr];
                float s = x0 + x1, q = x0 * x0 + x1 * x1;
#pragma unroll
                for (int off = 32; off; off >>= 1) { s += __shfl_xor(s, off); q += __shfl_xor(q, off); }
                float mu = s * (1.0f / 128.0f);
                float var = q * (1.0f / 128.0f) - mu * mu;
                float rs = rsqrtf(var + 1e-5f);
                int sw = (rloc & 7) << 4;
                *(ushort*)(smem + rloc * 256 + ((2 * l) ^ sw))        = f2bf((x0 - mu) * rs * gl0 + el0);
                *(ushort*)(smem + rloc * 256 + ((2 * (l + 64)) ^ sw)) = f2bf((x1 - mu) * rs * gl1 + el1);
            }
        }
    }
    asm volatile("s_waitcnt lgkmcnt(0)" ::: "memory");

    // ---- A-frags of yn (row lr)
    bf16x8 afr[4];
#pragma unroll
    for (int kf = 0; kf < 4; kf++) {
        afr[kf] = *(const bf16x8*)(smem + lr * 256 + ((16 * g + 64 * kf) ^ ((lr & 7) << 4)));
    }

    f32x4 oacc[8];
#pragma unroll
    for (int nt = 0; nt < 8; nt++) oacc[nt] = (f32x4){0.f, 0.f, 0.f, 0.f};

#pragma unroll
    for (int kb = 0; kb < 2; kb++) {
#pragma unroll
        for (int cc = 0; cc < 4; cc++) {
            // ---- stage 1: h chunk (32 H-cols) = relu(yn @ W1 + b1)
#pragma unroll
            for (int nt2 = 0; nt2 < 2; nt2++) {
                int nt = 2 * cc + nt2;
                f32x4 acc = (f32x4){0.f, 0.f, 0.f, 0.f};
#pragma unroll
                for (int kf = 0; kf < 4; kf++) {
                    bf16x8 bfr = *(const bf16x8*)(w1F + (((((kb << 3) | nt) << 2) | kf) << 9) + (l << 3));
                    acc = MFMA_B16(afr[kf], bfr, acc);
                }
                float bb1 = b1[128 * kb + 16 * nt + lr];
                int colc = lr + 16 * nt2;   // 0..31 within chunk
#pragma unroll
                for (int i = 0; i < 4; i++) {
                    int row = 4 * g + i;
                    int ad = 4096 + row * 64 + ((2 * colc) ^ ((row & 3) << 4));
                    *(ushort*)(smem + ad) = f2bf(fmaxf(acc[i] + bb1, 0.f));
                }
            }
            asm volatile("s_waitcnt lgkmcnt(0)" ::: "memory");

            // ---- stage 2: oacc += h_chunk @ W2[k-chunk, :]
            bf16x8 hfr = *(const bf16x8*)(smem + 4096 + lr * 64 + ((16 * g) ^ ((lr & 3) << 4)));
#pragma unroll
            for (int nt = 0; nt < 8; nt++) {
                bf16x8 bfr = *(const bf16x8*)(w2F + (((((kb << 3) | nt) << 2) | cc) << 9) + (l << 3));
                oacc[nt] = MFMA_B16(hfr, bfr, oacc[nt]);
            }
            asm volatile("s_waitcnt lgkmcnt(0)" ::: "memory");   // hscratch reads done before next chunk's writes
        }
    }

    // ---- epilogue: bounce delta (bf16) through yn region -> coalesced store
#pragma unroll
    for (int nt = 0; nt < 8; nt++) {
        int col = 16 * nt + lr;
#pragma unroll
        for (int i = 0; i < 4; i++) {
            int row = 4 * g + i;
            int ad = row * 256 + ((2 * col) ^ ((row & 7) << 4));
            *(ushort*)(smem + ad) = f2bf(oacc[nt][i]);
        }
    }
    asm volatile("s_waitcnt lgkmcnt(0)" ::: "memory");
    {
        float b20 = b2[l], b21 = b2[l + 64];
#pragma unroll
        for (int rr = 0; rr < 16; rr++) {
            int sw = (rr & 7) << 4;
            float d0 = lbf(*(const ushort*)(smem + rr * 256 + ((2 * l) ^ sw)));
            float d1 = lbf(*(const ushort*)(smem + rr * 256 + ((2 * (l + 64)) ^ sw)));
            size_t ro = (rbase + rr) * 128;
            x[ro + l]      = x[ro + l]      + d0 + b20;
            x[ro + l + 64] = x[ro + l + 64] + d1 + b21;
        }
    }
}

// ---------------------------------------------------------------------------
extern "C" void kernel_launch(void* const* d_in, const int* in_sizes, int n_in,
                              void* d_out, int out_size, void* d_ws, size_t ws_size,
                              hipStream_t stream)
{
    const float* seq   = (const float*)d_in[0];
    const float* pair  = (const float*)d_in[1];
    const float* sn_g  = (const float*)d_in[2];
    const float* sn_b  = (const float*)d_in[3];
    const float* Wq    = (const float*)d_in[4];
    const float* Wk    = (const float*)d_in[5];
    const float* Wyq   = (const float*)d_in[6];
    const float* Wyk   = (const float*)d_in[7];
    const float* Wdist = (const float*)d_in[8];
    const float* Wout  = (const float*)d_in[9];
    const float* bout  = (const float*)d_in[10];
    const float* rn_g  = (const float*)d_in[11];
    const float* rn_b  = (const float*)d_in[12];
    const float* Wrq   = (const float*)d_in[13];
    const float* Wrk   = (const float*)d_in[14];
    const float* Wrv   = (const float*)d_in[15];
    const float* brv   = (const float*)d_in[16];
    const float* Wro   = (const float*)d_in[17];
    const float* bro   = (const float*)d_in[18];
    const float* mn_g  = (const float*)d_in[19];
    const float* mn_b  = (const float*)d_in[20];
    const float* W1    = (const float*)d_in[21];
    const float* b1    = (const float*)d_in[22];
    const float* W2    = (const float*)d_in[23];
    const float* b2    = (const float*)d_in[24];
    (void)in_sizes; (void)n_in; (void)out_size; (void)ws_size;

    // ws: ~1.75 MB used
    float*  x2   = (float*)d_ws;          // [2,256,512]  262144 f32
    float*  a2   = x2 + 262144;           // [2,256,128]   65536 f32
    float*  c2   = a2 + 65536;            // [2,256,128]   65536 f32
    float*  wd2  = c2 + 65536;            // [3,128]+pad     512 f32
    ushort* wqF  = (ushort*)(wd2 + 512);  // frag-order 8192 each
    ushort* wkF  = wqF + 8192;
    ushort* wvF  = wkF + 8192;
    ushort* w1F  = wvF + 8192;            // frag-order 32768
    ushort* w2F  = w1F + 32768;           // frag-order 32768
    float*  xres = (float*)d_out;

    k_ln_pool  <<<512,   256, 0, stream>>>(seq, sn_g, sn_b, x2);
    k_proj     <<<512,   128, 0, stream>>>(x2, Wq, Wk, Wyq, Wyk, Wout, bout, a2, c2);
    k_wd2      <<<1,     128, 0, stream>>>(Wdist, Wout, wd2);
    k_wt       <<<48,    512, 0, stream>>>(Wrq, Wrk, Wrv, wqF, wkF, wvF);
    k_wt12     <<<128,   512, 0, stream>>>(W1, W2, w1F, w2F);
    k_assemble <<<65536, 256, 0, stream>>>(pair, a2, c2, wd2, xres);
    k_attn_mfma<<<512,   512, 0, stream>>>(xres, rn_g, rn_b, wqF, wkF, wvF, brv, Wro, bro);
    k_mlp_mfma <<<8192,  64,  0, stream>>>(xres, mn_g, mn_b, w1F, w2F, b1, b2);
}